// Round 7
// baseline (607.649 us; speedup 1.0000x reference)
//
#include <hip/hip_runtime.h>
#include <hip/hip_fp16.h>

// GraphNN_KNN: N=50000 nodes, E=800000 edges, H=64.
// msg = relu([x_i, x_j-x_i, ef] @ W + b) == relu(u[dst] + v[src] + ef*we)
// with u = x@(Wt-Wm)+b, v = x@Wm. u/v GEMMs use MFMA 16x16x32_f16 with
// split-fp16 inputs (3 product terms) for fp32-level accuracy; outputs fp16.
// Round 7: revert r6's padded CSR (count+fill fusion doubled k_front; dense
// CSR restored). NEW: emuv kernel fuses em-fold(order o) with uv GEMM(o+1)
// for the same 64-node tile — x' stays in LDS between the phases (kills the
// em->uv global x round-trip + grid drain, 9x per run). u/v ping-pong
// buffers remove the cross-block RAW hazard. em(o=3), lin, ec unchanged.

#define NN 50000
#define NE 800000
#define PER 200000      // E / 4 orders
#define HD 64
#define NKEY 250112     // 4*NN em keys + NN ec keys, padded to 977*256
#define GB_CNT 3125     // NE/256
#define GB_PREP 192     // 12*4096/256
#define GB_LIN 782      // ceil(NN/64)
#define GB_KEYS 977     // NKEY/256

typedef _Float16 half8 __attribute__((ext_vector_type(8)));
typedef float float4v __attribute__((ext_vector_type(4)));

struct UvLds {
    _Float16 wuh[64 * 72], wul[64 * 72], wvh[64 * 72], wvl[64 * 72];
    _Float16 rp[4 * 16 * 72];
};

struct EmuvLds {
    union {
        float xs[64][68];            // phase A out / phase B in (17.4KB)
        _Float16 rp[4 * 16 * 72];    // phase B repack (9.2KB, after barrier)
    } a;
    _Float16 wuh[64 * 72], wvh[64 * 72];   // W hi parts (18.4KB)
};                                          // total 35.8KB -> 4 blocks/CU

// ---------------- front mega-kernel: count | prep_w | lin0 -----------------
__global__ __launch_bounds__(256) void k_front(
        const int* __restrict__ ei, int* __restrict__ cnt,
        uchar2* __restrict__ rank,
        const float* __restrict__ em_w, const float* __restrict__ ec_w,
        _Float16* __restrict__ wh,
        const float* __restrict__ xin, const float* __restrict__ W0,
        const float* __restrict__ b0, float* __restrict__ x) {
    __shared__ float xs[64][11];
    int t = threadIdx.x;
    if (blockIdx.x < GB_CNT) {
        // ---- count (atomic histogram + rank capture) ----
        int e = blockIdx.x * 256 + t;           // grid exact: e < NE
        int src = ei[e];
        int dst = ei[NE + e];
        int o = e / PER;
        int r1 = atomicAdd(&cnt[o * NN + src], 1);
        int r2 = atomicAdd(&cnt[4 * NN + dst], 1);
        rank[e] = make_uchar2((unsigned char)r1, (unsigned char)r2);
    } else if (blockIdx.x < GB_CNT + GB_PREP) {
        // ---- weight prep: split-fp16, transposed [n][k] ----
        // mats 0-2 emWu, 3-5 emWv, 6-8 ecWu, 9-11 ecWv; lo parts at +12.
        int idx = (blockIdx.x - GB_CNT) * 256 + t;   // < 12*4096
        int mat = idx >> 12, pos = idx & 4095;
        int n = pos >> 6, k = pos & 63;
        float val;
        if (mat < 3)      { const float* B = em_w + mat * 129 * 64;     val = B[k*64+n] - B[(64+k)*64+n]; }
        else if (mat < 6) { const float* B = em_w + (mat-3) * 129 * 64; val = B[(64+k)*64+n]; }
        else if (mat < 9) { const float* B = ec_w + (mat-6) * 128 * 64; val = B[k*64+n] - B[(64+k)*64+n]; }
        else              { const float* B = ec_w + (mat-9) * 128 * 64; val = B[(64+k)*64+n]; }
        _Float16 h = (_Float16)val;
        _Float16 l = (_Float16)(val - (float)h);
        wh[(size_t)mat * 4096 + n * 64 + k] = h;
        wh[(size_t)(12 + mat) * 4096 + n * 64 + k] = l;
    } else {
        // ---- lin0: x = relu(xin @ W0 + b0), K=10 ----
        const int K = 10;
        int n0 = (blockIdx.x - GB_CNT - GB_PREP) * 64;
        for (int idx = t; idx < 64 * K; idx += 256) {
            int n = idx / K, k = idx - n * K;
            int g = n0 + n;
            xs[n][k] = (g < NN) ? xin[(size_t)g * K + k] : 0.f;
        }
        __syncthreads();
        int ng = t >> 4;
        int f0 = (t & 15) * 4;
        float acc[4][4] = {};
        for (int k = 0; k < K; ++k) {
            float4 w4 = *(const float4*)&W0[k * HD + f0];
            #pragma unroll
            for (int j = 0; j < 4; ++j) {
                float xv = xs[ng * 4 + j][k];
                acc[j][0] += xv * w4.x; acc[j][1] += xv * w4.y;
                acc[j][2] += xv * w4.z; acc[j][3] += xv * w4.w;
            }
        }
        float4 b4 = *(const float4*)&b0[f0];
        #pragma unroll
        for (int j = 0; j < 4; ++j) {
            int g = n0 + ng * 4 + j;
            if (g < NN) {
                float4 o;
                o.x = fmaxf(acc[j][0] + b4.x, 0.f);
                o.y = fmaxf(acc[j][1] + b4.y, 0.f);
                o.z = fmaxf(acc[j][2] + b4.z, 0.f);
                o.w = fmaxf(acc[j][3] + b4.w, 0.f);
                *(float4*)&x[(size_t)g * HD + f0] = o;
            }
        }
    }
}

// ---------------- scans (2 kernels) ----------------------------------------
__global__ __launch_bounds__(256) void scan_blk(
        const int* __restrict__ cnt, int* __restrict__ bsum) {
    __shared__ int s[256];
    int t = threadIdx.x;
    int i = blockIdx.x * 256 + t;
    int c = (i < NKEY) ? cnt[i] : 0;
    s[t] = c; __syncthreads();
    for (int d = 1; d < 256; d <<= 1) {
        int v = (t >= d) ? s[t - d] : 0;
        __syncthreads(); s[t] += v; __syncthreads();
    }
    if (t == 255) bsum[blockIdx.x] = s[255];
}

// per-block: recompute top-level exclusive prefix from bsum (<=4 loads/thread)
__global__ __launch_bounds__(256) void scan_fin2(
        const int* __restrict__ cnt, const int* __restrict__ bsum,
        int* __restrict__ ofs) {
    __shared__ int s[256];
    int t = threadIdx.x;
    int i = blockIdx.x * 256 + t;
    int pre = 0;
    for (int j = t; j < blockIdx.x; j += 256) pre += bsum[j];
    s[t] = pre; __syncthreads();
    for (int d = 128; d > 0; d >>= 1) {
        if (t < d) s[t] += s[t + d];
        __syncthreads();
    }
    int base = s[0];
    __syncthreads();
    int c = (i < NKEY) ? cnt[i] : 0;
    s[t] = c; __syncthreads();
    for (int d = 1; d < 256; d <<= 1) {
        int v = (t >= d) ? s[t - d] : 0;
        __syncthreads(); s[t] += v; __syncthreads();
    }
    if (i < NKEY) ofs[i] = base + s[t] - c;  // exclusive
}

// ---------------- u/v via MFMA, split-fp16 (standalone form) ---------------
__device__ __forceinline__ void uv_body(
        UvLds& L, int bid, const float* __restrict__ x,
        const _Float16* __restrict__ Wuh, const _Float16* __restrict__ Wul,
        const _Float16* __restrict__ Wvh, const _Float16* __restrict__ Wvl,
        const float* __restrict__ bias,
        _Float16* __restrict__ u, _Float16* __restrict__ v) {
    int t = threadIdx.x;
    int n0 = bid * 64;
    { // stage W (4 arrays), row remap into 72-padded LDS
        int n = t >> 2, c = (t & 3) * 16;
        *(half8*)&L.wuh[n * 72 + c]     = *(const half8*)&Wuh[n * 64 + c];
        *(half8*)&L.wuh[n * 72 + c + 8] = *(const half8*)&Wuh[n * 64 + c + 8];
        *(half8*)&L.wul[n * 72 + c]     = *(const half8*)&Wul[n * 64 + c];
        *(half8*)&L.wul[n * 72 + c + 8] = *(const half8*)&Wul[n * 64 + c + 8];
        *(half8*)&L.wvh[n * 72 + c]     = *(const half8*)&Wvh[n * 64 + c];
        *(half8*)&L.wvh[n * 72 + c + 8] = *(const half8*)&Wvh[n * 64 + c + 8];
        *(half8*)&L.wvl[n * 72 + c]     = *(const half8*)&Wvl[n * 64 + c];
        *(half8*)&L.wvl[n * 72 + c + 8] = *(const half8*)&Wvl[n * 64 + c + 8];
    }
    int w = t >> 6, lane = t & 63;
    int quad = lane >> 4, l16 = lane & 15;
    int m0 = w * 16;
    int row = n0 + m0 + l16;
    half8 ah0, ah1, al0, al1;
    {
        float f[16];
        if (row < NN) {
            const float4* p = (const float4*)&x[(size_t)row * HD + quad * 8];
            *(float4*)&f[0] = p[0]; *(float4*)&f[4] = p[1];
            const float4* q = (const float4*)&x[(size_t)row * HD + 32 + quad * 8];
            *(float4*)&f[8] = q[0]; *(float4*)&f[12] = q[1];
        } else {
            #pragma unroll
            for (int j = 0; j < 16; ++j) f[j] = 0.f;
        }
        #pragma unroll
        for (int j = 0; j < 8; ++j) {
            _Float16 h = (_Float16)f[j];
            ah0[j] = h; al0[j] = (_Float16)(f[j] - (float)h);
            _Float16 h2 = (_Float16)f[j + 8];
            ah1[j] = h2; al1[j] = (_Float16)(f[j + 8] - (float)h2);
        }
    }
    __syncthreads();

    float4v au[4], av[4];
    #pragma unroll
    for (int nt = 0; nt < 4; ++nt) {
        int n = nt * 16 + l16;
        half8 bh0 = *(half8*)&L.wuh[n * 72 + quad * 8];
        half8 bh1 = *(half8*)&L.wuh[n * 72 + 32 + quad * 8];
        half8 bl0 = *(half8*)&L.wul[n * 72 + quad * 8];
        half8 bl1 = *(half8*)&L.wul[n * 72 + 32 + quad * 8];
        float4v acc = {0.f, 0.f, 0.f, 0.f};
        acc = __builtin_amdgcn_mfma_f32_16x16x32_f16(ah0, bh0, acc, 0, 0, 0);
        acc = __builtin_amdgcn_mfma_f32_16x16x32_f16(ah1, bh1, acc, 0, 0, 0);
        acc = __builtin_amdgcn_mfma_f32_16x16x32_f16(al0, bh0, acc, 0, 0, 0);
        acc = __builtin_amdgcn_mfma_f32_16x16x32_f16(al1, bh1, acc, 0, 0, 0);
        acc = __builtin_amdgcn_mfma_f32_16x16x32_f16(ah0, bl0, acc, 0, 0, 0);
        acc = __builtin_amdgcn_mfma_f32_16x16x32_f16(ah1, bl1, acc, 0, 0, 0);
        au[nt] = acc;
        half8 ch0 = *(half8*)&L.wvh[n * 72 + quad * 8];
        half8 ch1 = *(half8*)&L.wvh[n * 72 + 32 + quad * 8];
        half8 cl0 = *(half8*)&L.wvl[n * 72 + quad * 8];
        half8 cl1 = *(half8*)&L.wvl[n * 72 + 32 + quad * 8];
        float4v accv = {0.f, 0.f, 0.f, 0.f};
        accv = __builtin_amdgcn_mfma_f32_16x16x32_f16(ah0, ch0, accv, 0, 0, 0);
        accv = __builtin_amdgcn_mfma_f32_16x16x32_f16(ah1, ch1, accv, 0, 0, 0);
        accv = __builtin_amdgcn_mfma_f32_16x16x32_f16(al0, ch0, accv, 0, 0, 0);
        accv = __builtin_amdgcn_mfma_f32_16x16x32_f16(al1, ch1, accv, 0, 0, 0);
        accv = __builtin_amdgcn_mfma_f32_16x16x32_f16(ah0, cl0, accv, 0, 0, 0);
        accv = __builtin_amdgcn_mfma_f32_16x16x32_f16(ah1, cl1, accv, 0, 0, 0);
        av[nt] = accv;
    }

    _Float16* rpw = &L.rp[w * 16 * 72];
    #pragma unroll
    for (int nt = 0; nt < 4; ++nt) {
        float bn = bias[nt * 16 + l16];
        #pragma unroll
        for (int r = 0; r < 4; ++r)
            rpw[(quad * 4 + r) * 72 + nt * 16 + l16] = (_Float16)(au[nt][r] + bn);
    }
    int mr = lane >> 2, cr = (lane & 3) * 16;
    int gr = n0 + m0 + mr;
    if (gr < NN) {
        *(half8*)&u[(size_t)gr * HD + cr]     = *(half8*)&rpw[mr * 72 + cr];
        *(half8*)&u[(size_t)gr * HD + cr + 8] = *(half8*)&rpw[mr * 72 + cr + 8];
    }
    #pragma unroll
    for (int nt = 0; nt < 4; ++nt) {
        #pragma unroll
        for (int r = 0; r < 4; ++r)
            rpw[(quad * 4 + r) * 72 + nt * 16 + l16] = (_Float16)(av[nt][r]);
    }
    if (gr < NN) {
        *(half8*)&v[(size_t)gr * HD + cr]     = *(half8*)&rpw[mr * 72 + cr];
        *(half8*)&v[(size_t)gr * HD + cr + 8] = *(half8*)&rpw[mr * 72 + cr + 8];
    }
}

__global__ __launch_bounds__(256) void uv_slim(
        const float* __restrict__ x,
        const _Float16* __restrict__ Wuh, const _Float16* __restrict__ Wul,
        const _Float16* __restrict__ Wvh, const _Float16* __restrict__ Wvl,
        const float* __restrict__ bias,
        _Float16* __restrict__ u, _Float16* __restrict__ v) {
    __shared__ UvLds L;
    uv_body(L, blockIdx.x, x, Wuh, Wul, Wvh, Wvl, bias, u, v);
}

// ---------------- fill + first uv fused ------------------------------------
__global__ __launch_bounds__(256) void k_fill_uv(
        const int* __restrict__ ei, const float* __restrict__ ef,
        const int* __restrict__ ofs, const uchar2* __restrict__ rank,
        unsigned* __restrict__ em_val, int* __restrict__ ec_val,
        const float* __restrict__ x,
        const _Float16* __restrict__ Wuh, const _Float16* __restrict__ Wul,
        const _Float16* __restrict__ Wvh, const _Float16* __restrict__ Wvl,
        const float* __restrict__ bias,
        _Float16* __restrict__ u, _Float16* __restrict__ v) {
    __shared__ UvLds L;
    if (blockIdx.x < GB_CNT) {
        int e = blockIdx.x * 256 + threadIdx.x;   // grid exact: e < NE
        int src = ei[e];
        int dst = ei[NE + e];
        int o = e / PER;
        uchar2 r = rank[e];
        int p1 = ofs[o * NN + src] + r.x;
        unsigned short eb = __half_as_ushort(__float2half_rn(ef[e]));
        em_val[p1] = ((unsigned)dst << 16) | (unsigned)eb;
        int p2 = ofs[4 * NN + dst] + r.y - NE;
        ec_val[p2] = src;
    } else {
        uv_body(L, blockIdx.x - GB_CNT, x, Wuh, Wul, Wvh, Wvl, bias, u, v);
    }
}

// load 8 consecutive halves (16B aligned) -> 8 floats
__device__ __forceinline__ void load_h8(const __half* p, float* o) {
    float4 r = *(const float4*)p;
    __half2 h0 = *reinterpret_cast<__half2*>(&r.x);
    __half2 h1 = *reinterpret_cast<__half2*>(&r.y);
    __half2 h2 = *reinterpret_cast<__half2*>(&r.z);
    __half2 h3 = *reinterpret_cast<__half2*>(&r.w);
    float2 f0 = __half22float2(h0), f1 = __half22float2(h1);
    float2 f2 = __half22float2(h2), f3 = __half22float2(h3);
    o[0] = f0.x; o[1] = f0.y; o[2] = f1.x; o[3] = f1.y;
    o[4] = f2.x; o[5] = f2.y; o[6] = f3.x; o[7] = f3.y;
}

// convert an already-loaded 16B of halves -> 8 floats
__device__ __forceinline__ void cvt_h8(float4 r, float* o) {
    __half2 h0 = *reinterpret_cast<__half2*>(&r.x);
    __half2 h1 = *reinterpret_cast<__half2*>(&r.y);
    __half2 h2 = *reinterpret_cast<__half2*>(&r.z);
    __half2 h3 = *reinterpret_cast<__half2*>(&r.w);
    float2 f0 = __half22float2(h0), f1 = __half22float2(h1);
    float2 f2 = __half22float2(h2), f3 = __half22float2(h3);
    o[0] = f0.x; o[1] = f0.y; o[2] = f1.x; o[3] = f1.y;
    o[4] = f2.x; o[5] = f2.y; o[6] = f3.x; o[7] = f3.y;
}

// ---------------- fused em(o) fold + uv(o+1) GEMM --------------------------
// Phase A: em fold for the block's 64 nodes (4 lanes/node, 16 feats/lane);
// x' written to global (next fold needs it) AND kept in LDS.
// Phase B: uv GEMM with A-frags from LDS x' (no global x re-read). W hi from
// LDS, W lo direct from L2-hot global. u/v ping-pong kills cross-block RAW.
__global__ __launch_bounds__(256) void emuv(
        const unsigned* __restrict__ em_val, const int* __restrict__ ofs,
        const __half* __restrict__ u_in, const __half* __restrict__ v_in,
        const float* __restrict__ we, int order, float* __restrict__ x,
        const _Float16* __restrict__ Wuh, const _Float16* __restrict__ Wul,
        const _Float16* __restrict__ Wvh, const _Float16* __restrict__ Wvl,
        const float* __restrict__ bias,
        _Float16* __restrict__ u_out, _Float16* __restrict__ v_out) {
    __shared__ EmuvLds L;
    int t = threadIdx.x;
    int n0 = blockIdx.x * 64;
    { // stage W hi parts
        int n = t >> 2, c = (t & 3) * 16;
        *(half8*)&L.wuh[n * 72 + c]     = *(const half8*)&Wuh[n * 64 + c];
        *(half8*)&L.wuh[n * 72 + c + 8] = *(const half8*)&Wuh[n * 64 + c + 8];
        *(half8*)&L.wvh[n * 72 + c]     = *(const half8*)&Wvh[n * 64 + c];
        *(half8*)&L.wvh[n * 72 + c + 8] = *(const half8*)&Wvh[n * 64 + c + 8];
    }
    // ---- phase A: em fold ----
    {
        int nd = t >> 2, sub = t & 3, f0 = sub * 16;
        int node = n0 + nd;
        if (node < NN) {
            float vn[16], wef[16], acc[16] = {};
            load_h8(&v_in[(size_t)node * HD + f0], vn);
            load_h8(&v_in[(size_t)node * HD + f0 + 8], vn + 8);
            *(float4*)&wef[0]  = *(const float4*)&we[f0];
            *(float4*)&wef[4]  = *(const float4*)&we[f0 + 4];
            *(float4*)&wef[8]  = *(const float4*)&we[f0 + 8];
            *(float4*)&wef[12] = *(const float4*)&we[f0 + 12];
            int key = order * NN + node;
            int s0 = ofs[key], s1 = ofs[key + 1];
            int p = s0;
            for (; p + 2 <= s1; p += 2) {
                unsigned e0 = em_val[p], e1 = em_val[p + 1];
                const __half* r0 = &u_in[(size_t)(e0 >> 16) * HD + f0];
                const __half* r1 = &u_in[(size_t)(e1 >> 16) * HD + f0];
                float u0[16], u1[16];
                load_h8(r0, u0); load_h8(r0 + 8, u0 + 8);
                load_h8(r1, u1); load_h8(r1 + 8, u1 + 8);
                float ef0 = __half2float(__ushort_as_half((unsigned short)(e0 & 0xffff)));
                float ef1 = __half2float(__ushort_as_half((unsigned short)(e1 & 0xffff)));
                #pragma unroll
                for (int j = 0; j < 16; ++j) {
                    acc[j] += fmaxf(u0[j] + vn[j] + ef0 * wef[j], 0.f)
                            + fmaxf(u1[j] + vn[j] + ef1 * wef[j], 0.f);
                }
            }
            if (p < s1) {
                unsigned e0 = em_val[p];
                const __half* r0 = &u_in[(size_t)(e0 >> 16) * HD + f0];
                float u0[16];
                load_h8(r0, u0); load_h8(r0 + 8, u0 + 8);
                float ef0 = __half2float(__ushort_as_half((unsigned short)(e0 & 0xffff)));
                #pragma unroll
                for (int j = 0; j < 16; ++j)
                    acc[j] += fmaxf(u0[j] + vn[j] + ef0 * wef[j], 0.f);
            }
            float xr[16];
            *(float4*)&xr[0]  = *(const float4*)&x[(size_t)node * HD + f0];
            *(float4*)&xr[4]  = *(const float4*)&x[(size_t)node * HD + f0 + 4];
            *(float4*)&xr[8]  = *(const float4*)&x[(size_t)node * HD + f0 + 8];
            *(float4*)&xr[12] = *(const float4*)&x[(size_t)node * HD + f0 + 12];
            #pragma unroll
            for (int j = 0; j < 16; ++j) xr[j] = (xr[j] + acc[j]) * 0.5f;
            *(float4*)&x[(size_t)node * HD + f0]      = *(float4*)&xr[0];
            *(float4*)&x[(size_t)node * HD + f0 + 4]  = *(float4*)&xr[4];
            *(float4*)&x[(size_t)node * HD + f0 + 8]  = *(float4*)&xr[8];
            *(float4*)&x[(size_t)node * HD + f0 + 12] = *(float4*)&xr[12];
            *(float4*)&L.a.xs[nd][f0]      = *(float4*)&xr[0];
            *(float4*)&L.a.xs[nd][f0 + 4]  = *(float4*)&xr[4];
            *(float4*)&L.a.xs[nd][f0 + 8]  = *(float4*)&xr[8];
            *(float4*)&L.a.xs[nd][f0 + 12] = *(float4*)&xr[12];
        } else {
            float4 z = {0.f, 0.f, 0.f, 0.f};
            *(float4*)&L.a.xs[nd][f0]      = z;
            *(float4*)&L.a.xs[nd][f0 + 4]  = z;
            *(float4*)&L.a.xs[nd][f0 + 8]  = z;
            *(float4*)&L.a.xs[nd][f0 + 12] = z;
        }
    }
    __syncthreads();
    // ---- phase B: uv GEMM from LDS x' ----
    int w = t >> 6, lane = t & 63;
    int quad = lane >> 4, l16 = lane & 15;
    int m0 = w * 16;
    int rowl = m0 + l16;
    half8 ah0, ah1, al0, al1;
    {
        float f[16];
        *(float4*)&f[0]  = *(float4*)&L.a.xs[rowl][quad * 8];
        *(float4*)&f[4]  = *(float4*)&L.a.xs[rowl][quad * 8 + 4];
        *(float4*)&f[8]  = *(float4*)&L.a.xs[rowl][32 + quad * 8];
        *(float4*)&f[12] = *(float4*)&L.a.xs[rowl][32 + quad * 8 + 4];
        #pragma unroll
        for (int j = 0; j < 8; ++j) {
            _Float16 h = (_Float16)f[j];
            ah0[j] = h; al0[j] = (_Float16)(f[j] - (float)h);
            _Float16 h2 = (_Float16)f[j + 8];
            ah1[j] = h2; al1[j] = (_Float16)(f[j + 8] - (float)h2);
        }
    }
    float4v au[4], av[4];
    #pragma unroll
    for (int nt = 0; nt < 4; ++nt) {
        int n = nt * 16 + l16;
        half8 bh0 = *(half8*)&L.wuh[n * 72 + quad * 8];
        half8 bh1 = *(half8*)&L.wuh[n * 72 + 32 + quad * 8];
        half8 bl0 = *(const half8*)&Wul[n * 64 + quad * 8];
        half8 bl1 = *(const half8*)&Wul[n * 64 + 32 + quad * 8];
        float4v acc = {0.f, 0.f, 0.f, 0.f};
        acc = __builtin_amdgcn_mfma_f32_16x16x32_f16(ah0, bh0, acc, 0, 0, 0);
        acc = __builtin_amdgcn_mfma_f32_16x16x32_f16(ah1, bh1, acc, 0, 0, 0);
        acc = __builtin_amdgcn_mfma_f32_16x16x32_f16(al0, bh0, acc, 0, 0, 0);
        acc = __builtin_amdgcn_mfma_f32_16x16x32_f16(al1, bh1, acc, 0, 0, 0);
        acc = __builtin_amdgcn_mfma_f32_16x16x32_f16(ah0, bl0, acc, 0, 0, 0);
        acc = __builtin_amdgcn_mfma_f32_16x16x32_f16(ah1, bl1, acc, 0, 0, 0);
        au[nt] = acc;
        half8 ch0 = *(half8*)&L.wvh[n * 72 + quad * 8];
        half8 ch1 = *(half8*)&L.wvh[n * 72 + 32 + quad * 8];
        half8 cl0 = *(const half8*)&Wvl[n * 64 + quad * 8];
        half8 cl1 = *(const half8*)&Wvl[n * 64 + 32 + quad * 8];
        float4v accv = {0.f, 0.f, 0.f, 0.f};
        accv = __builtin_amdgcn_mfma_f32_16x16x32_f16(ah0, ch0, accv, 0, 0, 0);
        accv = __builtin_amdgcn_mfma_f32_16x16x32_f16(ah1, ch1, accv, 0, 0, 0);
        accv = __builtin_amdgcn_mfma_f32_16x16x32_f16(al0, ch0, accv, 0, 0, 0);
        accv = __builtin_amdgcn_mfma_f32_16x16x32_f16(al1, ch1, accv, 0, 0, 0);
        accv = __builtin_amdgcn_mfma_f32_16x16x32_f16(ah0, cl0, accv, 0, 0, 0);
        accv = __builtin_amdgcn_mfma_f32_16x16x32_f16(ah1, cl1, accv, 0, 0, 0);
        av[nt] = accv;
    }
    __syncthreads();   // all xs reads done -> rp may alias
    _Float16* rpw = &L.a.rp[w * 16 * 72];
    #pragma unroll
    for (int nt = 0; nt < 4; ++nt) {
        float bn = bias[nt * 16 + l16];
        #pragma unroll
        for (int r = 0; r < 4; ++r)
            rpw[(quad * 4 + r) * 72 + nt * 16 + l16] = (_Float16)(au[nt][r] + bn);
    }
    int mr = lane >> 2, cr = (lane & 3) * 16;
    int gr = n0 + m0 + mr;
    if (gr < NN) {
        *(half8*)&u_out[(size_t)gr * HD + cr]     = *(half8*)&rpw[mr * 72 + cr];
        *(half8*)&u_out[(size_t)gr * HD + cr + 8] = *(half8*)&rpw[mr * 72 + cr + 8];
    }
    #pragma unroll
    for (int nt = 0; nt < 4; ++nt) {
        #pragma unroll
        for (int r = 0; r < 4; ++r)
            rpw[(quad * 4 + r) * 72 + nt * 16 + l16] = (_Float16)(av[nt][r]);
    }
    if (gr < NN) {
        *(half8*)&v_out[(size_t)gr * HD + cr]     = *(half8*)&rpw[mr * 72 + cr];
        *(half8*)&v_out[(size_t)gr * HD + cr + 8] = *(half8*)&rpw[mr * 72 + cr + 8];
    }
}

// ---------------- emulsion edge pass + fold (standalone, order 3) ----------
__device__ __forceinline__ void em_consume(
        unsigned e, float4 r, const float* vn, const float* wef, float* acc) {
    float uj[8];
    cvt_h8(r, uj);
    float ef = __half2float(__ushort_as_half((unsigned short)(e & 0xffff)));
    #pragma unroll
    for (int j = 0; j < 8; ++j)
        acc[j] += fmaxf(uj[j] + vn[j] + ef * wef[j], 0.f);
}

__global__ __launch_bounds__(256) void em_edge(
        const unsigned* __restrict__ em_val, const int* __restrict__ ofs,
        const __half* __restrict__ u, const __half* __restrict__ v,
        const float* __restrict__ we, float* __restrict__ x, int order) {
    int t = threadIdx.x;
    int node = blockIdx.x * 32 + (t >> 3);
    if (node >= NN) return;
    int f0 = (t & 7) * 8;
    int key = order * NN + node;
    int s0 = ofs[key], s1 = ofs[key + 1];
    float vn[8], wef[8], acc[8] = {};
    load_h8(&v[(size_t)node * HD + f0], vn);
    *(float4*)&wef[0] = *(const float4*)&we[f0];
    *(float4*)&wef[4] = *(const float4*)&we[f0 + 4];
    int p = s0, n = s1 - s0;
    unsigned ia0 = 0, ia1 = 0, ja0 = 0, ja1 = 0;
    float4 ra, rb;
    if (n >= 2) {
        ia0 = em_val[p]; ia1 = em_val[p + 1];
        ra = *(const float4*)&u[(size_t)(ia0 >> 16) * HD + f0];
        rb = *(const float4*)&u[(size_t)(ia1 >> 16) * HD + f0];
    }
    if (n >= 4) { ja0 = em_val[p + 2]; ja1 = em_val[p + 3]; }
    for (; p + 6 <= s1; p += 2) {
        float4 qa = *(const float4*)&u[(size_t)(ja0 >> 16) * HD + f0];
        float4 qb = *(const float4*)&u[(size_t)(ja1 >> 16) * HD + f0];
        unsigned ka0 = em_val[p + 4], ka1 = em_val[p + 5];
        em_consume(ia0, ra, vn, wef, acc);
        em_consume(ia1, rb, vn, wef, acc);
        ia0 = ja0; ia1 = ja1; ra = qa; rb = qb; ja0 = ka0; ja1 = ka1;
    }
    if (n >= 4) {
        float4 qa = *(const float4*)&u[(size_t)(ja0 >> 16) * HD + f0];
        float4 qb = *(const float4*)&u[(size_t)(ja1 >> 16) * HD + f0];
        em_consume(ia0, ra, vn, wef, acc);
        em_consume(ia1, rb, vn, wef, acc);
        em_consume(ja0, qa, vn, wef, acc);
        em_consume(ja1, qb, vn, wef, acc);
        p += 4;
    } else if (n >= 2) {
        em_consume(ia0, ra, vn, wef, acc);
        em_consume(ia1, rb, vn, wef, acc);
        p += 2;
    }
    if (p < s1) {
        unsigned e0 = em_val[p];
        float4 r0 = *(const float4*)&u[(size_t)(e0 >> 16) * HD + f0];
        em_consume(e0, r0, vn, wef, acc);
    }
    float xr[8];
    *(float4*)&xr[0] = *(const float4*)&x[(size_t)node * HD + f0];
    *(float4*)&xr[4] = *(const float4*)&x[(size_t)node * HD + f0 + 4];
    #pragma unroll
    for (int j = 0; j < 8; ++j) xr[j] = (xr[j] + acc[j]) * 0.5f;
    *(float4*)&x[(size_t)node * HD + f0] = *(float4*)&xr[0];
    *(float4*)&x[(size_t)node * HD + f0 + 4] = *(float4*)&xr[4];
}

// ---------------- edge conv pass -------------------------------------------
__device__ __forceinline__ void ec_consume(float4 r, half8& m) {
    union { float4 f; half8 h; } uu; uu.f = r;
    m = __builtin_elementwise_max(m, uu.h);
}

__global__ __launch_bounds__(256) void ec_edge(
        const int* __restrict__ ec_val, const int* __restrict__ ofs,
        const __half* __restrict__ u, const __half* __restrict__ v,
        float* __restrict__ x) {
    int t = threadIdx.x;
    int node = blockIdx.x * 32 + (t >> 3);
    if (node >= NN) return;
    int f0 = (t & 7) * 8;
    int s0 = ofs[4 * NN + node] - NE, s1 = ofs[4 * NN + node + 1] - NE;
    int n = s1 - s0;
    float o[8];
    if (n > 0) {
        half8 m8;
        #pragma unroll
        for (int j = 0; j < 8; ++j) m8[j] = (_Float16)(-65504.f);
        int p = s0;
        int ja0 = 0, ja1 = 0;
        float4 ra, rb;
        if (n >= 2) {
            int ia0 = ec_val[p], ia1 = ec_val[p + 1];
            ra = *(const float4*)&v[(size_t)ia0 * HD + f0];
            rb = *(const float4*)&v[(size_t)ia1 * HD + f0];
        }
        if (n >= 4) { ja0 = ec_val[p + 2]; ja1 = ec_val[p + 3]; }
        for (; p + 6 <= s1; p += 2) {
            float4 qa = *(const float4*)&v[(size_t)ja0 * HD + f0];
            float4 qb = *(const float4*)&v[(size_t)ja1 * HD + f0];
            int ka0 = ec_val[p + 4], ka1 = ec_val[p + 5];
            ec_consume(ra, m8);
            ec_consume(rb, m8);
            ra = qa; rb = qb; ja0 = ka0; ja1 = ka1;
        }
        if (n >= 4) {
            float4 qa = *(const float4*)&v[(size_t)ja0 * HD + f0];
            float4 qb = *(const float4*)&v[(size_t)ja1 * HD + f0];
            ec_consume(ra, m8);
            ec_consume(rb, m8);
            ec_consume(qa, m8);
            ec_consume(qb, m8);
            p += 4;
        } else if (n >= 2) {
            ec_consume(ra, m8);
            ec_consume(rb, m8);
            p += 2;
        }
        if (p < s1) {
            int i0 = ec_val[p];
            float4 r0 = *(const float4*)&v[(size_t)i0 * HD + f0];
            ec_consume(r0, m8);
        }
        float un[8];
        load_h8(&u[(size_t)node * HD + f0], un);
        #pragma unroll
        for (int j = 0; j < 8; ++j)
            o[j] = fmaxf(un[j] + (float)m8[j], 0.f);
    } else {
        #pragma unroll
        for (int j = 0; j < 8; ++j) o[j] = 0.f;
    }
    *(float4*)&x[(size_t)node * HD + f0] = *(float4*)&o[0];
    *(float4*)&x[(size_t)node * HD + f0 + 4] = *(float4*)&o[4];
}

// ---------------- linear: x = relu(x @ W + b), scalar fp32 ------------------
template<int K>
__global__ __launch_bounds__(256) void lin_kernel(
        const float* __restrict__ xin,
        const float* __restrict__ W, const float* __restrict__ bias,
        float* __restrict__ xout) {
    __shared__ float xs[64][K + 1];
    int t = threadIdx.x;
    int n0 = blockIdx.x * 64;
    for (int idx = t; idx < 64 * K; idx += 256) {
        int n = idx / K, k = idx - n * K;
        int g = n0 + n;
        xs[n][k] = (g < NN) ? xin[(size_t)g * K + k] : 0.f;
    }
    __syncthreads();
    int ng = t >> 4;
    int f0 = (t & 15) * 4;
    float acc[4][4] = {};
    for (int k = 0; k < K; ++k) {
        float4 w4 = *(const float4*)&W[k * HD + f0];
        #pragma unroll
        for (int j = 0; j < 4; ++j) {
            float xv = xs[ng * 4 + j][k];
            acc[j][0] += xv * w4.x; acc[j][1] += xv * w4.y;
            acc[j][2] += xv * w4.z; acc[j][3] += xv * w4.w;
        }
    }
    float4 b4 = *(const float4*)&bias[f0];
    #pragma unroll
    for (int j = 0; j < 4; ++j) {
        int g = n0 + ng * 4 + j;
        if (g < NN) {
            float4 o;
            o.x = fmaxf(acc[j][0] + b4.x, 0.f);
            o.y = fmaxf(acc[j][1] + b4.y, 0.f);
            o.z = fmaxf(acc[j][2] + b4.z, 0.f);
            o.w = fmaxf(acc[j][3] + b4.w, 0.f);
            *(float4*)&xout[(size_t)g * HD + f0] = o;
        }
    }
}

// ---------------- output projection (chunked, low VGPR) ---------------------
__global__ __launch_bounds__(256) void out_kernel(
        const float* __restrict__ x, const float* __restrict__ W,
        const float* __restrict__ bias, float* __restrict__ out) {
    int n = blockIdx.x * 256 + threadIdx.x;
    if (n >= NN) return;
    float acc[10];
    #pragma unroll
    for (int f = 0; f < 10; ++f) acc[f] = bias[f];
    #pragma unroll
    for (int k0 = 0; k0 < HD; k0 += 16) {
        float xr[16];
        #pragma unroll
        for (int k = 0; k < 16; k += 4)
            *(float4*)&xr[k] = *(const float4*)&x[(size_t)n * HD + k0 + k];
        #pragma unroll
        for (int k = 0; k < 16; ++k) {
            #pragma unroll
            for (int f = 0; f < 10; ++f)
                acc[f] += xr[k] * W[(k0 + k) * 10 + f];
        }
    }
    #pragma unroll
    for (int f = 0; f < 10; ++f) out[(size_t)n * 10 + f] = acc[f];
}

extern "C" void kernel_launch(void* const* d_in, const int* in_sizes, int n_in,
                              void* d_out, int out_size, void* d_ws, size_t ws_size,
                              hipStream_t stream) {
    const float* x_in  = (const float*)d_in[0];
    const int*   ei    = (const int*)d_in[1];
    const float* ef    = (const float*)d_in[2];
    const float* lw[3] = {(const float*)d_in[3], (const float*)d_in[5], (const float*)d_in[7]};
    const float* lb[3] = {(const float*)d_in[4], (const float*)d_in[6], (const float*)d_in[8]};
    const float* em_w  = (const float*)d_in[9];
    const float* em_b  = (const float*)d_in[10];
    const float* ec_w  = (const float*)d_in[11];
    const float* ec_b  = (const float*)d_in[12];
    const float* ow    = (const float*)d_in[13];
    const float* ob    = (const float*)d_in[14];
    float* out = (float*)d_out;

    char* wsb = (char*)d_ws;
    size_t off = 0;
    auto alloc = [&](size_t bytes) {
        void* p = wsb + off;
        off = (off + bytes + 255) & ~(size_t)255;
        return p;
    };
    float*     x      = (float*)alloc((size_t)NN * HD * 4);
    _Float16*  u      = (_Float16*)alloc((size_t)NN * HD * 2);
    _Float16*  v      = (_Float16*)alloc((size_t)NN * HD * 2);
    _Float16*  u2     = (_Float16*)alloc((size_t)NN * HD * 2);
    _Float16*  v2     = (_Float16*)alloc((size_t)NN * HD * 2);
    int*       cnt    = (int*)alloc((size_t)NKEY * 4);
    int*       ofs    = (int*)alloc((size_t)NKEY * 4);
    int*       bsum   = (int*)alloc((size_t)1024 * 4);
    uchar2*    rank   = (uchar2*)alloc((size_t)NE * 2);
    unsigned*  em_val = (unsigned*)alloc((size_t)NE * 4);
    int*       ec_val = (int*)alloc((size_t)NE * 4);
    _Float16*  wh     = (_Float16*)alloc((size_t)24 * 4096 * 2);
    (void)ws_size; (void)in_sizes; (void)n_in; (void)out_size;

    const int gb_n8 = (NN + 31) / 32;   // 1563

    // ---- CSR build + weight prep + lin0 (fused front) ----
    hipMemsetAsync(cnt, 0, (size_t)NKEY * 4, stream);
    k_front<<<GB_CNT + GB_PREP + GB_LIN, 256, 0, stream>>>(
        ei, cnt, rank, em_w, ec_w, wh, x_in, lw[0], lb[0], x);
    scan_blk<<<GB_KEYS, 256, 0, stream>>>(cnt, bsum);
    scan_fin2<<<GB_KEYS, 256, 0, stream>>>(cnt, bsum, ofs);

    // fill fused with layer-0/order-0 uv GEMM (writes buf0 = u,v)
    k_fill_uv<<<GB_CNT + GB_LIN, 256, 0, stream>>>(
        ei, ef, ofs, rank, em_val, ec_val, x,
        wh, wh + (size_t)12 * 4096, wh + (size_t)3 * 4096, wh + (size_t)15 * 4096,
        em_b, u, v);

    // ---- network ----
    for (int i = 0; i < 3; ++i) {
        const _Float16* Wuh = wh + (size_t)i * 4096;
        const _Float16* Wvh = wh + (size_t)(3 + i) * 4096;
        const _Float16* Wul = wh + (size_t)(12 + i) * 4096;
        const _Float16* Wvl = wh + (size_t)(15 + i) * 4096;
        const float* bi = em_b + (size_t)i * HD;
        const float* we = em_w + (size_t)i * 129 * HD + 128 * HD;
        if (i > 0)
            uv_slim<<<GB_LIN, 256, 0, stream>>>(x, Wuh, Wul, Wvh, Wvl, bi, u, v);
        // fused fold(o) + uv(o+1), ping-pong u/v buffers
        emuv<<<GB_LIN, 256, 0, stream>>>(em_val, ofs, (const __half*)u,
            (const __half*)v, we, 0, x, Wuh, Wul, Wvh, Wvl, bi, u2, v2);
        emuv<<<GB_LIN, 256, 0, stream>>>(em_val, ofs, (const __half*)u2,
            (const __half*)v2, we, 1, x, Wuh, Wul, Wvh, Wvl, bi, u, v);
        emuv<<<GB_LIN, 256, 0, stream>>>(em_val, ofs, (const __half*)u,
            (const __half*)v, we, 2, x, Wuh, Wul, Wvh, Wvl, bi, u2, v2);
        // final fold of the layer (order 3) reads buf1
        em_edge<<<gb_n8, 256, 0, stream>>>(em_val, ofs, (const __half*)u2,
                                           (const __half*)v2, we, x, 3);
        if (i < 2)
            lin_kernel<64><<<GB_LIN, 256, 0, stream>>>(x, lw[i + 1], lb[i + 1], x);
    }

    for (int j = 0; j < 3; ++j) {
        const _Float16* Wuh = wh + (size_t)(6 + j) * 4096;
        const _Float16* Wvh = wh + (size_t)(9 + j) * 4096;
        const _Float16* Wul = wh + (size_t)(18 + j) * 4096;
        const _Float16* Wvl = wh + (size_t)(21 + j) * 4096;
        const float* bj = ec_b + (size_t)j * HD;
        uv_slim<<<GB_LIN, 256, 0, stream>>>(x, Wuh, Wul, Wvh, Wvl, bj, u, v);
        ec_edge<<<gb_n8, 256, 0, stream>>>(ec_val, ofs, (const __half*)u,
                                           (const __half*)v, x);
    }

    out_kernel<<<(NN + 255) / 256, 256, 0, stream>>>(x, ow, ob, out);
}

// Round 8
// 586.863 us; speedup vs baseline: 1.0354x; 1.0354x over previous
//
#include <hip/hip_runtime.h>
#include <hip/hip_fp16.h>

// GraphNN_KNN: N=50000 nodes, E=800000 edges, H=64.
// msg = relu([x_i, x_j-x_i, ef] @ W + b) == relu(u[dst] + v[src] + ef*we)
// with u = x@(Wt-Wm)+b, v = x@Wm. u/v GEMMs use MFMA 16x16x32_f16 with
// split-fp16 inputs (3 product terms) for fp32-level accuracy; outputs fp16.
// Round 8: revert r7's emuv fusion (LDS capped gather phase at 16 waves/CU —
// gathers are wave-count-bound). NEW: edge passes use 16 lanes/node (4 feats
// x 8B gathers/lane) -> 2x waves (12500) -> full 32 waves/CU residency
// (was 24.4). Same 3-stage pipeline + packed-fp16 max. Rest = r5.

#define NN 50000
#define NE 800000
#define PER 200000      // E / 4 orders
#define HD 64
#define NKEY 250112     // 4*NN em keys + NN ec keys, padded to 977*256
#define GB_CNT 3125     // NE/256
#define GB_PREP 192     // 12*4096/256
#define GB_LIN 782      // ceil(NN/64)
#define GB_KEYS 977     // NKEY/256

typedef _Float16 half8 __attribute__((ext_vector_type(8)));
typedef _Float16 half4 __attribute__((ext_vector_type(4)));
typedef float float4v __attribute__((ext_vector_type(4)));

struct UvLds {
    _Float16 wuh[64 * 72], wul[64 * 72], wvh[64 * 72], wvl[64 * 72];
    _Float16 rp[4 * 16 * 72];
};

// ---------------- front mega-kernel: count | prep_w | lin0 -----------------
__global__ __launch_bounds__(256) void k_front(
        const int* __restrict__ ei, int* __restrict__ cnt,
        uchar2* __restrict__ rank,
        const float* __restrict__ em_w, const float* __restrict__ ec_w,
        _Float16* __restrict__ wh,
        const float* __restrict__ xin, const float* __restrict__ W0,
        const float* __restrict__ b0, float* __restrict__ x) {
    __shared__ float xs[64][11];
    int t = threadIdx.x;
    if (blockIdx.x < GB_CNT) {
        // ---- count (atomic histogram + rank capture) ----
        int e = blockIdx.x * 256 + t;           // grid exact: e < NE
        int src = ei[e];
        int dst = ei[NE + e];
        int o = e / PER;
        int r1 = atomicAdd(&cnt[o * NN + src], 1);
        int r2 = atomicAdd(&cnt[4 * NN + dst], 1);
        rank[e] = make_uchar2((unsigned char)r1, (unsigned char)r2);
    } else if (blockIdx.x < GB_CNT + GB_PREP) {
        // ---- weight prep: split-fp16, transposed [n][k] ----
        // mats 0-2 emWu, 3-5 emWv, 6-8 ecWu, 9-11 ecWv; lo parts at +12.
        int idx = (blockIdx.x - GB_CNT) * 256 + t;   // < 12*4096
        int mat = idx >> 12, pos = idx & 4095;
        int n = pos >> 6, k = pos & 63;
        float val;
        if (mat < 3)      { const float* B = em_w + mat * 129 * 64;     val = B[k*64+n] - B[(64+k)*64+n]; }
        else if (mat < 6) { const float* B = em_w + (mat-3) * 129 * 64; val = B[(64+k)*64+n]; }
        else if (mat < 9) { const float* B = ec_w + (mat-6) * 128 * 64; val = B[k*64+n] - B[(64+k)*64+n]; }
        else              { const float* B = ec_w + (mat-9) * 128 * 64; val = B[(64+k)*64+n]; }
        _Float16 h = (_Float16)val;
        _Float16 l = (_Float16)(val - (float)h);
        wh[(size_t)mat * 4096 + n * 64 + k] = h;
        wh[(size_t)(12 + mat) * 4096 + n * 64 + k] = l;
    } else {
        // ---- lin0: x = relu(xin @ W0 + b0), K=10 ----
        const int K = 10;
        int n0 = (blockIdx.x - GB_CNT - GB_PREP) * 64;
        for (int idx = t; idx < 64 * K; idx += 256) {
            int n = idx / K, k = idx - n * K;
            int g = n0 + n;
            xs[n][k] = (g < NN) ? xin[(size_t)g * K + k] : 0.f;
        }
        __syncthreads();
        int ng = t >> 4;
        int f0 = (t & 15) * 4;
        float acc[4][4] = {};
        for (int k = 0; k < K; ++k) {
            float4 w4 = *(const float4*)&W0[k * HD + f0];
            #pragma unroll
            for (int j = 0; j < 4; ++j) {
                float xv = xs[ng * 4 + j][k];
                acc[j][0] += xv * w4.x; acc[j][1] += xv * w4.y;
                acc[j][2] += xv * w4.z; acc[j][3] += xv * w4.w;
            }
        }
        float4 b4 = *(const float4*)&b0[f0];
        #pragma unroll
        for (int j = 0; j < 4; ++j) {
            int g = n0 + ng * 4 + j;
            if (g < NN) {
                float4 o;
                o.x = fmaxf(acc[j][0] + b4.x, 0.f);
                o.y = fmaxf(acc[j][1] + b4.y, 0.f);
                o.z = fmaxf(acc[j][2] + b4.z, 0.f);
                o.w = fmaxf(acc[j][3] + b4.w, 0.f);
                *(float4*)&x[(size_t)g * HD + f0] = o;
            }
        }
    }
}

// ---------------- scans (2 kernels) ----------------------------------------
__global__ __launch_bounds__(256) void scan_blk(
        const int* __restrict__ cnt, int* __restrict__ bsum) {
    __shared__ int s[256];
    int t = threadIdx.x;
    int i = blockIdx.x * 256 + t;
    int c = (i < NKEY) ? cnt[i] : 0;
    s[t] = c; __syncthreads();
    for (int d = 1; d < 256; d <<= 1) {
        int v = (t >= d) ? s[t - d] : 0;
        __syncthreads(); s[t] += v; __syncthreads();
    }
    if (t == 255) bsum[blockIdx.x] = s[255];
}

// per-block: recompute top-level exclusive prefix from bsum (<=4 loads/thread)
__global__ __launch_bounds__(256) void scan_fin2(
        const int* __restrict__ cnt, const int* __restrict__ bsum,
        int* __restrict__ ofs) {
    __shared__ int s[256];
    int t = threadIdx.x;
    int i = blockIdx.x * 256 + t;
    int pre = 0;
    for (int j = t; j < blockIdx.x; j += 256) pre += bsum[j];
    s[t] = pre; __syncthreads();
    for (int d = 128; d > 0; d >>= 1) {
        if (t < d) s[t] += s[t + d];
        __syncthreads();
    }
    int base = s[0];
    __syncthreads();
    int c = (i < NKEY) ? cnt[i] : 0;
    s[t] = c; __syncthreads();
    for (int d = 1; d < 256; d <<= 1) {
        int v = (t >= d) ? s[t - d] : 0;
        __syncthreads(); s[t] += v; __syncthreads();
    }
    if (i < NKEY) ofs[i] = base + s[t] - c;  // exclusive
}

// ---------------- u/v via MFMA, split-fp16 ---------------------------------
// 64 nodes/block, 4 waves. A-frags lane-private straight from global; W in
// LDS (shared by all waves, 72-padded); rp for output repack.
__device__ __forceinline__ void uv_body(
        UvLds& L, int bid, const float* __restrict__ x,
        const _Float16* __restrict__ Wuh, const _Float16* __restrict__ Wul,
        const _Float16* __restrict__ Wvh, const _Float16* __restrict__ Wvl,
        const float* __restrict__ bias,
        _Float16* __restrict__ u, _Float16* __restrict__ v) {
    int t = threadIdx.x;
    int n0 = bid * 64;
    { // stage W (4 arrays), row remap into 72-padded LDS
        int n = t >> 2, c = (t & 3) * 16;
        *(half8*)&L.wuh[n * 72 + c]     = *(const half8*)&Wuh[n * 64 + c];
        *(half8*)&L.wuh[n * 72 + c + 8] = *(const half8*)&Wuh[n * 64 + c + 8];
        *(half8*)&L.wul[n * 72 + c]     = *(const half8*)&Wul[n * 64 + c];
        *(half8*)&L.wul[n * 72 + c + 8] = *(const half8*)&Wul[n * 64 + c + 8];
        *(half8*)&L.wvh[n * 72 + c]     = *(const half8*)&Wvh[n * 64 + c];
        *(half8*)&L.wvh[n * 72 + c + 8] = *(const half8*)&Wvh[n * 64 + c + 8];
        *(half8*)&L.wvl[n * 72 + c]     = *(const half8*)&Wvl[n * 64 + c];
        *(half8*)&L.wvl[n * 72 + c + 8] = *(const half8*)&Wvl[n * 64 + c + 8];
    }
    int w = t >> 6, lane = t & 63;
    int quad = lane >> 4, l16 = lane & 15;
    int m0 = w * 16;
    int row = n0 + m0 + l16;
    half8 ah0, ah1, al0, al1;
    {
        float f[16];
        if (row < NN) {
            const float4* p = (const float4*)&x[(size_t)row * HD + quad * 8];
            *(float4*)&f[0] = p[0]; *(float4*)&f[4] = p[1];
            const float4* q = (const float4*)&x[(size_t)row * HD + 32 + quad * 8];
            *(float4*)&f[8] = q[0]; *(float4*)&f[12] = q[1];
        } else {
            #pragma unroll
            for (int j = 0; j < 16; ++j) f[j] = 0.f;
        }
        #pragma unroll
        for (int j = 0; j < 8; ++j) {
            _Float16 h = (_Float16)f[j];
            ah0[j] = h; al0[j] = (_Float16)(f[j] - (float)h);
            _Float16 h2 = (_Float16)f[j + 8];
            ah1[j] = h2; al1[j] = (_Float16)(f[j + 8] - (float)h2);
        }
    }
    __syncthreads();

    float4v au[4], av[4];
    #pragma unroll
    for (int nt = 0; nt < 4; ++nt) {
        int n = nt * 16 + l16;
        half8 bh0 = *(half8*)&L.wuh[n * 72 + quad * 8];
        half8 bh1 = *(half8*)&L.wuh[n * 72 + 32 + quad * 8];
        half8 bl0 = *(half8*)&L.wul[n * 72 + quad * 8];
        half8 bl1 = *(half8*)&L.wul[n * 72 + 32 + quad * 8];
        float4v acc = {0.f, 0.f, 0.f, 0.f};
        acc = __builtin_amdgcn_mfma_f32_16x16x32_f16(ah0, bh0, acc, 0, 0, 0);
        acc = __builtin_amdgcn_mfma_f32_16x16x32_f16(ah1, bh1, acc, 0, 0, 0);
        acc = __builtin_amdgcn_mfma_f32_16x16x32_f16(al0, bh0, acc, 0, 0, 0);
        acc = __builtin_amdgcn_mfma_f32_16x16x32_f16(al1, bh1, acc, 0, 0, 0);
        acc = __builtin_amdgcn_mfma_f32_16x16x32_f16(ah0, bl0, acc, 0, 0, 0);
        acc = __builtin_amdgcn_mfma_f32_16x16x32_f16(ah1, bl1, acc, 0, 0, 0);
        au[nt] = acc;
        half8 ch0 = *(half8*)&L.wvh[n * 72 + quad * 8];
        half8 ch1 = *(half8*)&L.wvh[n * 72 + 32 + quad * 8];
        half8 cl0 = *(half8*)&L.wvl[n * 72 + quad * 8];
        half8 cl1 = *(half8*)&L.wvl[n * 72 + 32 + quad * 8];
        float4v accv = {0.f, 0.f, 0.f, 0.f};
        accv = __builtin_amdgcn_mfma_f32_16x16x32_f16(ah0, ch0, accv, 0, 0, 0);
        accv = __builtin_amdgcn_mfma_f32_16x16x32_f16(ah1, ch1, accv, 0, 0, 0);
        accv = __builtin_amdgcn_mfma_f32_16x16x32_f16(al0, ch0, accv, 0, 0, 0);
        accv = __builtin_amdgcn_mfma_f32_16x16x32_f16(al1, ch1, accv, 0, 0, 0);
        accv = __builtin_amdgcn_mfma_f32_16x16x32_f16(ah0, cl0, accv, 0, 0, 0);
        accv = __builtin_amdgcn_mfma_f32_16x16x32_f16(ah1, cl1, accv, 0, 0, 0);
        av[nt] = accv;
    }

    _Float16* rpw = &L.rp[w * 16 * 72];
    #pragma unroll
    for (int nt = 0; nt < 4; ++nt) {
        float bn = bias[nt * 16 + l16];
        #pragma unroll
        for (int r = 0; r < 4; ++r)
            rpw[(quad * 4 + r) * 72 + nt * 16 + l16] = (_Float16)(au[nt][r] + bn);
    }
    int mr = lane >> 2, cr = (lane & 3) * 16;
    int gr = n0 + m0 + mr;
    if (gr < NN) {
        *(half8*)&u[(size_t)gr * HD + cr]     = *(half8*)&rpw[mr * 72 + cr];
        *(half8*)&u[(size_t)gr * HD + cr + 8] = *(half8*)&rpw[mr * 72 + cr + 8];
    }
    #pragma unroll
    for (int nt = 0; nt < 4; ++nt) {
        #pragma unroll
        for (int r = 0; r < 4; ++r)
            rpw[(quad * 4 + r) * 72 + nt * 16 + l16] = (_Float16)(av[nt][r]);
    }
    if (gr < NN) {
        *(half8*)&v[(size_t)gr * HD + cr]     = *(half8*)&rpw[mr * 72 + cr];
        *(half8*)&v[(size_t)gr * HD + cr + 8] = *(half8*)&rpw[mr * 72 + cr + 8];
    }
}

__global__ __launch_bounds__(256) void uv_slim(
        const float* __restrict__ x,
        const _Float16* __restrict__ Wuh, const _Float16* __restrict__ Wul,
        const _Float16* __restrict__ Wvh, const _Float16* __restrict__ Wvl,
        const float* __restrict__ bias,
        _Float16* __restrict__ u, _Float16* __restrict__ v) {
    __shared__ UvLds L;
    uv_body(L, blockIdx.x, x, Wuh, Wul, Wvh, Wvl, bias, u, v);
}

// ---------------- fill + first uv fused ------------------------------------
__global__ __launch_bounds__(256) void k_fill_uv(
        const int* __restrict__ ei, const float* __restrict__ ef,
        const int* __restrict__ ofs, const uchar2* __restrict__ rank,
        unsigned* __restrict__ em_val, int* __restrict__ ec_val,
        const float* __restrict__ x,
        const _Float16* __restrict__ Wuh, const _Float16* __restrict__ Wul,
        const _Float16* __restrict__ Wvh, const _Float16* __restrict__ Wvl,
        const float* __restrict__ bias,
        _Float16* __restrict__ u, _Float16* __restrict__ v) {
    __shared__ UvLds L;
    if (blockIdx.x < GB_CNT) {
        int e = blockIdx.x * 256 + threadIdx.x;   // grid exact: e < NE
        int src = ei[e];
        int dst = ei[NE + e];
        int o = e / PER;
        uchar2 r = rank[e];
        int p1 = ofs[o * NN + src] + r.x;
        unsigned short eb = __half_as_ushort(__float2half_rn(ef[e]));
        em_val[p1] = ((unsigned)dst << 16) | (unsigned)eb;
        int p2 = ofs[4 * NN + dst] + r.y - NE;
        ec_val[p2] = src;
    } else {
        uv_body(L, blockIdx.x - GB_CNT, x, Wuh, Wul, Wvh, Wvl, bias, u, v);
    }
}

// convert an already-loaded 8B of halves -> 4 floats
__device__ __forceinline__ void cvt_h4(float2 r, float* o) {
    __half2 h0 = *reinterpret_cast<__half2*>(&r.x);
    __half2 h1 = *reinterpret_cast<__half2*>(&r.y);
    float2 f0 = __half22float2(h0), f1 = __half22float2(h1);
    o[0] = f0.x; o[1] = f0.y; o[2] = f1.x; o[3] = f1.y;
}

__device__ __forceinline__ void load_h4(const __half* p, float* o) {
    cvt_h4(*(const float2*)p, o);
}

// ---------------- emulsion edge pass + fold --------------------------------
// 16 lanes/node, 4 features x 8B gather per lane -> 12500 waves -> full
// 32-wave/CU residency (was 24.4 at 8 lanes/node). 3-stage pipeline:
// idx pair i+2 || rows pair i+1 || consume pair i.
// x[n] = (x[n] + sum_e relu(u[dst]+v[n]+ef*we)) / 2
__device__ __forceinline__ void em_consume(
        unsigned e, float2 r, const float* vn, const float* wef, float* acc) {
    float uj[4];
    cvt_h4(r, uj);
    float ef = __half2float(__ushort_as_half((unsigned short)(e & 0xffff)));
    #pragma unroll
    for (int j = 0; j < 4; ++j)
        acc[j] += fmaxf(uj[j] + vn[j] + ef * wef[j], 0.f);
}

__global__ __launch_bounds__(256) void em_edge(
        const unsigned* __restrict__ em_val, const int* __restrict__ ofs,
        const __half* __restrict__ u, const __half* __restrict__ v,
        const float* __restrict__ we, float* __restrict__ x, int order) {
    int t = threadIdx.x;
    int node = blockIdx.x * 16 + (t >> 4);
    if (node >= NN) return;
    int f0 = (t & 15) * 4;
    int key = order * NN + node;
    int s0 = ofs[key], s1 = ofs[key + 1];
    float vn[4], wef[4], acc[4] = {};
    load_h4(&v[(size_t)node * HD + f0], vn);
    *(float4*)&wef[0] = *(const float4*)&we[f0];
    int p = s0, n = s1 - s0;
    unsigned ia0 = 0, ia1 = 0, ja0 = 0, ja1 = 0;
    float2 ra, rb;
    if (n >= 2) {
        ia0 = em_val[p]; ia1 = em_val[p + 1];
        ra = *(const float2*)&u[(size_t)(ia0 >> 16) * HD + f0];
        rb = *(const float2*)&u[(size_t)(ia1 >> 16) * HD + f0];
    }
    if (n >= 4) { ja0 = em_val[p + 2]; ja1 = em_val[p + 3]; }
    for (; p + 6 <= s1; p += 2) {
        float2 qa = *(const float2*)&u[(size_t)(ja0 >> 16) * HD + f0];
        float2 qb = *(const float2*)&u[(size_t)(ja1 >> 16) * HD + f0];
        unsigned ka0 = em_val[p + 4], ka1 = em_val[p + 5];
        em_consume(ia0, ra, vn, wef, acc);
        em_consume(ia1, rb, vn, wef, acc);
        ia0 = ja0; ia1 = ja1; ra = qa; rb = qb; ja0 = ka0; ja1 = ka1;
    }
    if (n >= 4) {
        float2 qa = *(const float2*)&u[(size_t)(ja0 >> 16) * HD + f0];
        float2 qb = *(const float2*)&u[(size_t)(ja1 >> 16) * HD + f0];
        em_consume(ia0, ra, vn, wef, acc);
        em_consume(ia1, rb, vn, wef, acc);
        em_consume(ja0, qa, vn, wef, acc);
        em_consume(ja1, qb, vn, wef, acc);
        p += 4;
    } else if (n >= 2) {
        em_consume(ia0, ra, vn, wef, acc);
        em_consume(ia1, rb, vn, wef, acc);
        p += 2;
    }
    if (p < s1) {
        unsigned e0 = em_val[p];
        float2 r0 = *(const float2*)&u[(size_t)(e0 >> 16) * HD + f0];
        em_consume(e0, r0, vn, wef, acc);
    }
    float xr[4];
    *(float4*)&xr[0] = *(const float4*)&x[(size_t)node * HD + f0];
    #pragma unroll
    for (int j = 0; j < 4; ++j) xr[j] = (xr[j] + acc[j]) * 0.5f;
    *(float4*)&x[(size_t)node * HD + f0] = *(float4*)&xr[0];
}

// ---------------- edge conv pass -------------------------------------------
// max_e relu(u[n]+v[src]) == relu(u[n] + max_e v[src]) (fp-exact). 16 lanes/
// node, 8B gathers; running max in packed fp16 (half4 +
// __builtin_elementwise_max -> v_pk_max_f16; exact). 3-stage pipeline.
__device__ __forceinline__ void ec_consume(float2 r, half4& m) {
    union { float2 f; half4 h; } uu; uu.f = r;
    m = __builtin_elementwise_max(m, uu.h);
}

__global__ __launch_bounds__(256) void ec_edge(
        const int* __restrict__ ec_val, const int* __restrict__ ofs,
        const __half* __restrict__ u, const __half* __restrict__ v,
        float* __restrict__ x) {
    int t = threadIdx.x;
    int node = blockIdx.x * 16 + (t >> 4);
    if (node >= NN) return;
    int f0 = (t & 15) * 4;
    int s0 = ofs[4 * NN + node] - NE, s1 = ofs[4 * NN + node + 1] - NE;
    int n = s1 - s0;
    float o[4];
    if (n > 0) {
        half4 m4;
        #pragma unroll
        for (int j = 0; j < 4; ++j) m4[j] = (_Float16)(-65504.f);
        int p = s0;
        int ja0 = 0, ja1 = 0;
        float2 ra, rb;
        if (n >= 2) {
            int ia0 = ec_val[p], ia1 = ec_val[p + 1];
            ra = *(const float2*)&v[(size_t)ia0 * HD + f0];
            rb = *(const float2*)&v[(size_t)ia1 * HD + f0];
        }
        if (n >= 4) { ja0 = ec_val[p + 2]; ja1 = ec_val[p + 3]; }
        for (; p + 6 <= s1; p += 2) {
            float2 qa = *(const float2*)&v[(size_t)ja0 * HD + f0];
            float2 qb = *(const float2*)&v[(size_t)ja1 * HD + f0];
            int ka0 = ec_val[p + 4], ka1 = ec_val[p + 5];
            ec_consume(ra, m4);
            ec_consume(rb, m4);
            ra = qa; rb = qb; ja0 = ka0; ja1 = ka1;
        }
        if (n >= 4) {
            float2 qa = *(const float2*)&v[(size_t)ja0 * HD + f0];
            float2 qb = *(const float2*)&v[(size_t)ja1 * HD + f0];
            ec_consume(ra, m4);
            ec_consume(rb, m4);
            ec_consume(qa, m4);
            ec_consume(qb, m4);
            p += 4;
        } else if (n >= 2) {
            ec_consume(ra, m4);
            ec_consume(rb, m4);
            p += 2;
        }
        if (p < s1) {
            int i0 = ec_val[p];
            float2 r0 = *(const float2*)&v[(size_t)i0 * HD + f0];
            ec_consume(r0, m4);
        }
        float un[4];
        load_h4(&u[(size_t)node * HD + f0], un);
        #pragma unroll
        for (int j = 0; j < 4; ++j)
            o[j] = fmaxf(un[j] + (float)m4[j], 0.f);
    } else {
        #pragma unroll
        for (int j = 0; j < 4; ++j) o[j] = 0.f;
    }
    *(float4*)&x[(size_t)node * HD + f0] = *(float4*)&o[0];
}

// ---------------- linear: x = relu(x @ W + b), scalar fp32 ------------------
template<int K>
__global__ __launch_bounds__(256) void lin_kernel(
        const float* __restrict__ xin,
        const float* __restrict__ W, const float* __restrict__ bias,
        float* __restrict__ xout) {
    __shared__ float xs[64][K + 1];
    int t = threadIdx.x;
    int n0 = blockIdx.x * 64;
    for (int idx = t; idx < 64 * K; idx += 256) {
        int n = idx / K, k = idx - n * K;
        int g = n0 + n;
        xs[n][k] = (g < NN) ? xin[(size_t)g * K + k] : 0.f;
    }
    __syncthreads();
    int ng = t >> 4;
    int f0 = (t & 15) * 4;
    float acc[4][4] = {};
    for (int k = 0; k < K; ++k) {
        float4 w4 = *(const float4*)&W[k * HD + f0];
        #pragma unroll
        for (int j = 0; j < 4; ++j) {
            float xv = xs[ng * 4 + j][k];
            acc[j][0] += xv * w4.x; acc[j][1] += xv * w4.y;
            acc[j][2] += xv * w4.z; acc[j][3] += xv * w4.w;
        }
    }
    float4 b4 = *(const float4*)&bias[f0];
    #pragma unroll
    for (int j = 0; j < 4; ++j) {
        int g = n0 + ng * 4 + j;
        if (g < NN) {
            float4 o;
            o.x = fmaxf(acc[j][0] + b4.x, 0.f);
            o.y = fmaxf(acc[j][1] + b4.y, 0.f);
            o.z = fmaxf(acc[j][2] + b4.z, 0.f);
            o.w = fmaxf(acc[j][3] + b4.w, 0.f);
            *(float4*)&xout[(size_t)g * HD + f0] = o;
        }
    }
}

// ---------------- output projection (chunked, low VGPR) ---------------------
__global__ __launch_bounds__(256) void out_kernel(
        const float* __restrict__ x, const float* __restrict__ W,
        const float* __restrict__ bias, float* __restrict__ out) {
    int n = blockIdx.x * 256 + threadIdx.x;
    if (n >= NN) return;
    float acc[10];
    #pragma unroll
    for (int f = 0; f < 10; ++f) acc[f] = bias[f];
    #pragma unroll
    for (int k0 = 0; k0 < HD; k0 += 16) {
        float xr[16];
        #pragma unroll
        for (int k = 0; k < 16; k += 4)
            *(float4*)&xr[k] = *(const float4*)&x[(size_t)n * HD + k0 + k];
        #pragma unroll
        for (int k = 0; k < 16; ++k) {
            #pragma unroll
            for (int f = 0; f < 10; ++f)
                acc[f] += xr[k] * W[(k0 + k) * 10 + f];
        }
    }
    #pragma unroll
    for (int f = 0; f < 10; ++f) out[(size_t)n * 10 + f] = acc[f];
}

extern "C" void kernel_launch(void* const* d_in, const int* in_sizes, int n_in,
                              void* d_out, int out_size, void* d_ws, size_t ws_size,
                              hipStream_t stream) {
    const float* x_in  = (const float*)d_in[0];
    const int*   ei    = (const int*)d_in[1];
    const float* ef    = (const float*)d_in[2];
    const float* lw[3] = {(const float*)d_in[3], (const float*)d_in[5], (const float*)d_in[7]};
    const float* lb[3] = {(const float*)d_in[4], (const float*)d_in[6], (const float*)d_in[8]};
    const float* em_w  = (const float*)d_in[9];
    const float* em_b  = (const float*)d_in[10];
    const float* ec_w  = (const float*)d_in[11];
    const float* ec_b  = (const float*)d_in[12];
    const float* ow    = (const float*)d_in[13];
    const float* ob    = (const float*)d_in[14];
    float* out = (float*)d_out;

    char* wsb = (char*)d_ws;
    size_t off = 0;
    auto alloc = [&](size_t bytes) {
        void* p = wsb + off;
        off = (off + bytes + 255) & ~(size_t)255;
        return p;
    };
    float*     x      = (float*)alloc((size_t)NN * HD * 4);
    _Float16*  u      = (_Float16*)alloc((size_t)NN * HD * 2);
    _Float16*  v      = (_Float16*)alloc((size_t)NN * HD * 2);
    int*       cnt    = (int*)alloc((size_t)NKEY * 4);
    int*       ofs    = (int*)alloc((size_t)NKEY * 4);
    int*       bsum   = (int*)alloc((size_t)1024 * 4);
    uchar2*    rank   = (uchar2*)alloc((size_t)NE * 2);
    unsigned*  em_val = (unsigned*)alloc((size_t)NE * 4);
    int*       ec_val = (int*)alloc((size_t)NE * 4);
    _Float16*  wh     = (_Float16*)alloc((size_t)24 * 4096 * 2);
    (void)ws_size; (void)in_sizes; (void)n_in; (void)out_size;

    const int gb_n16 = (NN + 15) / 16;   // 3125

    // ---- CSR build + weight prep + lin0 (fused front) ----
    hipMemsetAsync(cnt, 0, (size_t)NKEY * 4, stream);
    k_front<<<GB_CNT + GB_PREP + GB_LIN, 256, 0, stream>>>(
        ei, cnt, rank, em_w, ec_w, wh, x_in, lw[0], lb[0], x);
    scan_blk<<<GB_KEYS, 256, 0, stream>>>(cnt, bsum);
    scan_fin2<<<GB_KEYS, 256, 0, stream>>>(cnt, bsum, ofs);

    // fill fused with layer-0/order-0 uv GEMM
    k_fill_uv<<<GB_CNT + GB_LIN, 256, 0, stream>>>(
        ei, ef, ofs, rank, em_val, ec_val, x,
        wh, wh + (size_t)12 * 4096, wh + (size_t)3 * 4096, wh + (size_t)15 * 4096,
        em_b, u, v);

    // ---- network ----
    for (int i = 0; i < 3; ++i) {
        const _Float16* Wuh = wh + (size_t)i * 4096;
        const _Float16* Wvh = wh + (size_t)(3 + i) * 4096;
        const _Float16* Wul = wh + (size_t)(12 + i) * 4096;
        const _Float16* Wvl = wh + (size_t)(15 + i) * 4096;
        const float* bi = em_b + (size_t)i * HD;
        const float* we = em_w + (size_t)i * 129 * HD + 128 * HD;
        for (int o = 0; o < 4; ++o) {
            if (!(i == 0 && o == 0))
                uv_slim<<<GB_LIN, 256, 0, stream>>>(x, Wuh, Wul, Wvh, Wvl, bi, u, v);
            em_edge<<<gb_n16, 256, 0, stream>>>(em_val, ofs, (const __half*)u,
                                                (const __half*)v, we, x, o);
        }
        if (i < 2)
            lin_kernel<64><<<GB_LIN, 256, 0, stream>>>(x, lw[i + 1], lb[i + 1], x);
    }

    for (int j = 0; j < 3; ++j) {
        const _Float16* Wuh = wh + (size_t)(6 + j) * 4096;
        const _Float16* Wvh = wh + (size_t)(9 + j) * 4096;
        const _Float16* Wul = wh + (size_t)(18 + j) * 4096;
        const _Float16* Wvl = wh + (size_t)(21 + j) * 4096;
        const float* bj = ec_b + (size_t)j * HD;
        uv_slim<<<GB_LIN, 256, 0, stream>>>(x, Wuh, Wul, Wvh, Wvl, bj, u, v);
        ec_edge<<<gb_n16, 256, 0, stream>>>(ec_val, ofs, (const __half*)u,
                                            (const __half*)v, x);
    }

    out_kernel<<<(NN + 255) / 256, 256, 0, stream>>>(x, ow, ob, out);
}

// Round 9
// 566.758 us; speedup vs baseline: 1.0721x; 1.0355x over previous
//
#include <hip/hip_runtime.h>
#include <hip/hip_fp16.h>

// GraphNN_KNN: N=50000 nodes, E=800000 edges, H=64.
// msg = relu([x_i, x_j-x_i, ef] @ W + b) == relu(u[dst] + v[src] + ef*we)
// with u = x@(Wt-Wm)+b, v = x@Wm. u/v GEMMs use MFMA 16x16x32_f16 with
// split-fp16 inputs (3 product terms) for fp32-level accuracy; outputs fp16.
// FINAL (round 9): exact restore of the round-3 configuration — the
// empirical minimum (567.6 us) across 9 structural variants. Edge passes:
// 8 nodes/wave, 8 lanes/node, 2-deep software-pipelined 16B gathers.
// Falsified alternatives (kept out): W-direct (r2 +150us), padded CSR
// (r6 +26), em+uv LDS fusion (r7 +40), 16-lane/8B gathers (r8 +19),
// 3-stage pipeline + packed-fp16 max (r5 +5, noise).

#define NN 50000
#define NE 800000
#define PER 200000      // E / 4 orders
#define HD 64
#define NKEY 250112     // 4*NN em keys + NN ec keys, padded to 977*256
#define GB_CNT 3125     // NE/256
#define GB_PREP 192     // 12*4096/256
#define GB_LIN 782      // ceil(NN/64)
#define GB_KEYS 977     // NKEY/256

typedef _Float16 half8 __attribute__((ext_vector_type(8)));
typedef float float4v __attribute__((ext_vector_type(4)));

struct UvLds {
    _Float16 wuh[64 * 72], wul[64 * 72], wvh[64 * 72], wvl[64 * 72];
    _Float16 rp[4 * 16 * 72];
};

// ---------------- front mega-kernel: count | prep_w | lin0 -----------------
__global__ __launch_bounds__(256) void k_front(
        const int* __restrict__ ei, int* __restrict__ cnt,
        uchar2* __restrict__ rank,
        const float* __restrict__ em_w, const float* __restrict__ ec_w,
        _Float16* __restrict__ wh,
        const float* __restrict__ xin, const float* __restrict__ W0,
        const float* __restrict__ b0, float* __restrict__ x) {
    __shared__ float xs[64][11];
    int t = threadIdx.x;
    if (blockIdx.x < GB_CNT) {
        // ---- count (atomic histogram + rank capture) ----
        int e = blockIdx.x * 256 + t;           // grid exact: e < NE
        int src = ei[e];
        int dst = ei[NE + e];
        int o = e / PER;
        int r1 = atomicAdd(&cnt[o * NN + src], 1);
        int r2 = atomicAdd(&cnt[4 * NN + dst], 1);
        rank[e] = make_uchar2((unsigned char)r1, (unsigned char)r2);
    } else if (blockIdx.x < GB_CNT + GB_PREP) {
        // ---- weight prep: split-fp16, transposed [n][k] ----
        // mats 0-2 emWu, 3-5 emWv, 6-8 ecWu, 9-11 ecWv; lo parts at +12.
        int idx = (blockIdx.x - GB_CNT) * 256 + t;   // < 12*4096
        int mat = idx >> 12, pos = idx & 4095;
        int n = pos >> 6, k = pos & 63;
        float val;
        if (mat < 3)      { const float* B = em_w + mat * 129 * 64;     val = B[k*64+n] - B[(64+k)*64+n]; }
        else if (mat < 6) { const float* B = em_w + (mat-3) * 129 * 64; val = B[(64+k)*64+n]; }
        else if (mat < 9) { const float* B = ec_w + (mat-6) * 128 * 64; val = B[k*64+n] - B[(64+k)*64+n]; }
        else              { const float* B = ec_w + (mat-9) * 128 * 64; val = B[(64+k)*64+n]; }
        _Float16 h = (_Float16)val;
        _Float16 l = (_Float16)(val - (float)h);
        wh[(size_t)mat * 4096 + n * 64 + k] = h;
        wh[(size_t)(12 + mat) * 4096 + n * 64 + k] = l;
    } else {
        // ---- lin0: x = relu(xin @ W0 + b0), K=10 ----
        const int K = 10;
        int n0 = (blockIdx.x - GB_CNT - GB_PREP) * 64;
        for (int idx = t; idx < 64 * K; idx += 256) {
            int n = idx / K, k = idx - n * K;
            int g = n0 + n;
            xs[n][k] = (g < NN) ? xin[(size_t)g * K + k] : 0.f;
        }
        __syncthreads();
        int ng = t >> 4;
        int f0 = (t & 15) * 4;
        float acc[4][4] = {};
        for (int k = 0; k < K; ++k) {
            float4 w4 = *(const float4*)&W0[k * HD + f0];
            #pragma unroll
            for (int j = 0; j < 4; ++j) {
                float xv = xs[ng * 4 + j][k];
                acc[j][0] += xv * w4.x; acc[j][1] += xv * w4.y;
                acc[j][2] += xv * w4.z; acc[j][3] += xv * w4.w;
            }
        }
        float4 b4 = *(const float4*)&b0[f0];
        #pragma unroll
        for (int j = 0; j < 4; ++j) {
            int g = n0 + ng * 4 + j;
            if (g < NN) {
                float4 o;
                o.x = fmaxf(acc[j][0] + b4.x, 0.f);
                o.y = fmaxf(acc[j][1] + b4.y, 0.f);
                o.z = fmaxf(acc[j][2] + b4.z, 0.f);
                o.w = fmaxf(acc[j][3] + b4.w, 0.f);
                *(float4*)&x[(size_t)g * HD + f0] = o;
            }
        }
    }
}

// ---------------- scans (2 kernels) ----------------------------------------
__global__ __launch_bounds__(256) void scan_blk(
        const int* __restrict__ cnt, int* __restrict__ bsum) {
    __shared__ int s[256];
    int t = threadIdx.x;
    int i = blockIdx.x * 256 + t;
    int c = (i < NKEY) ? cnt[i] : 0;
    s[t] = c; __syncthreads();
    for (int d = 1; d < 256; d <<= 1) {
        int v = (t >= d) ? s[t - d] : 0;
        __syncthreads(); s[t] += v; __syncthreads();
    }
    if (t == 255) bsum[blockIdx.x] = s[255];
}

// per-block: recompute top-level exclusive prefix from bsum (<=4 loads/thread)
__global__ __launch_bounds__(256) void scan_fin2(
        const int* __restrict__ cnt, const int* __restrict__ bsum,
        int* __restrict__ ofs) {
    __shared__ int s[256];
    int t = threadIdx.x;
    int i = blockIdx.x * 256 + t;
    int pre = 0;
    for (int j = t; j < blockIdx.x; j += 256) pre += bsum[j];
    s[t] = pre; __syncthreads();
    for (int d = 128; d > 0; d >>= 1) {
        if (t < d) s[t] += s[t + d];
        __syncthreads();
    }
    int base = s[0];
    __syncthreads();
    int c = (i < NKEY) ? cnt[i] : 0;
    s[t] = c; __syncthreads();
    for (int d = 1; d < 256; d <<= 1) {
        int v = (t >= d) ? s[t - d] : 0;
        __syncthreads(); s[t] += v; __syncthreads();
    }
    if (i < NKEY) ofs[i] = base + s[t] - c;  // exclusive
}

// ---------------- u/v via MFMA, split-fp16 ---------------------------------
// 64 nodes/block, 4 waves. A-frags lane-private straight from global; W in
// LDS (shared by all waves, 72-padded); rp for output repack.
__device__ __forceinline__ void uv_body(
        UvLds& L, int bid, const float* __restrict__ x,
        const _Float16* __restrict__ Wuh, const _Float16* __restrict__ Wul,
        const _Float16* __restrict__ Wvh, const _Float16* __restrict__ Wvl,
        const float* __restrict__ bias,
        _Float16* __restrict__ u, _Float16* __restrict__ v) {
    int t = threadIdx.x;
    int n0 = bid * 64;
    { // stage W (4 arrays), row remap into 72-padded LDS
        int n = t >> 2, c = (t & 3) * 16;
        *(half8*)&L.wuh[n * 72 + c]     = *(const half8*)&Wuh[n * 64 + c];
        *(half8*)&L.wuh[n * 72 + c + 8] = *(const half8*)&Wuh[n * 64 + c + 8];
        *(half8*)&L.wul[n * 72 + c]     = *(const half8*)&Wul[n * 64 + c];
        *(half8*)&L.wul[n * 72 + c + 8] = *(const half8*)&Wul[n * 64 + c + 8];
        *(half8*)&L.wvh[n * 72 + c]     = *(const half8*)&Wvh[n * 64 + c];
        *(half8*)&L.wvh[n * 72 + c + 8] = *(const half8*)&Wvh[n * 64 + c + 8];
        *(half8*)&L.wvl[n * 72 + c]     = *(const half8*)&Wvl[n * 64 + c];
        *(half8*)&L.wvl[n * 72 + c + 8] = *(const half8*)&Wvl[n * 64 + c + 8];
    }
    int w = t >> 6, lane = t & 63;
    int quad = lane >> 4, l16 = lane & 15;
    int m0 = w * 16;
    int row = n0 + m0 + l16;
    // A-frags: lane-private, direct from global, split in regs
    half8 ah0, ah1, al0, al1;
    {
        float f[16];
        if (row < NN) {
            const float4* p = (const float4*)&x[(size_t)row * HD + quad * 8];
            *(float4*)&f[0] = p[0]; *(float4*)&f[4] = p[1];
            const float4* q = (const float4*)&x[(size_t)row * HD + 32 + quad * 8];
            *(float4*)&f[8] = q[0]; *(float4*)&f[12] = q[1];
        } else {
            #pragma unroll
            for (int j = 0; j < 16; ++j) f[j] = 0.f;
        }
        #pragma unroll
        for (int j = 0; j < 8; ++j) {
            _Float16 h = (_Float16)f[j];
            ah0[j] = h; al0[j] = (_Float16)(f[j] - (float)h);
            _Float16 h2 = (_Float16)f[j + 8];
            ah1[j] = h2; al1[j] = (_Float16)(f[j + 8] - (float)h2);
        }
    }
    __syncthreads();

    float4v au[4], av[4];
    #pragma unroll
    for (int nt = 0; nt < 4; ++nt) {
        int n = nt * 16 + l16;
        half8 bh0 = *(half8*)&L.wuh[n * 72 + quad * 8];
        half8 bh1 = *(half8*)&L.wuh[n * 72 + 32 + quad * 8];
        half8 bl0 = *(half8*)&L.wul[n * 72 + quad * 8];
        half8 bl1 = *(half8*)&L.wul[n * 72 + 32 + quad * 8];
        float4v acc = {0.f, 0.f, 0.f, 0.f};
        acc = __builtin_amdgcn_mfma_f32_16x16x32_f16(ah0, bh0, acc, 0, 0, 0);
        acc = __builtin_amdgcn_mfma_f32_16x16x32_f16(ah1, bh1, acc, 0, 0, 0);
        acc = __builtin_amdgcn_mfma_f32_16x16x32_f16(al0, bh0, acc, 0, 0, 0);
        acc = __builtin_amdgcn_mfma_f32_16x16x32_f16(al1, bh1, acc, 0, 0, 0);
        acc = __builtin_amdgcn_mfma_f32_16x16x32_f16(ah0, bl0, acc, 0, 0, 0);
        acc = __builtin_amdgcn_mfma_f32_16x16x32_f16(ah1, bl1, acc, 0, 0, 0);
        au[nt] = acc;
        half8 ch0 = *(half8*)&L.wvh[n * 72 + quad * 8];
        half8 ch1 = *(half8*)&L.wvh[n * 72 + 32 + quad * 8];
        half8 cl0 = *(half8*)&L.wvl[n * 72 + quad * 8];
        half8 cl1 = *(half8*)&L.wvl[n * 72 + 32 + quad * 8];
        float4v accv = {0.f, 0.f, 0.f, 0.f};
        accv = __builtin_amdgcn_mfma_f32_16x16x32_f16(ah0, ch0, accv, 0, 0, 0);
        accv = __builtin_amdgcn_mfma_f32_16x16x32_f16(ah1, ch1, accv, 0, 0, 0);
        accv = __builtin_amdgcn_mfma_f32_16x16x32_f16(al0, ch0, accv, 0, 0, 0);
        accv = __builtin_amdgcn_mfma_f32_16x16x32_f16(al1, ch1, accv, 0, 0, 0);
        accv = __builtin_amdgcn_mfma_f32_16x16x32_f16(ah0, cl0, accv, 0, 0, 0);
        accv = __builtin_amdgcn_mfma_f32_16x16x32_f16(ah1, cl1, accv, 0, 0, 0);
        av[nt] = accv;
    }

    // repack u (+bias) through per-wave LDS, store 16B vectors
    _Float16* rpw = &L.rp[w * 16 * 72];
    #pragma unroll
    for (int nt = 0; nt < 4; ++nt) {
        float bn = bias[nt * 16 + l16];
        #pragma unroll
        for (int r = 0; r < 4; ++r)
            rpw[(quad * 4 + r) * 72 + nt * 16 + l16] = (_Float16)(au[nt][r] + bn);
    }
    int mr = lane >> 2, cr = (lane & 3) * 16;
    int gr = n0 + m0 + mr;
    if (gr < NN) {
        *(half8*)&u[(size_t)gr * HD + cr]     = *(half8*)&rpw[mr * 72 + cr];
        *(half8*)&u[(size_t)gr * HD + cr + 8] = *(half8*)&rpw[mr * 72 + cr + 8];
    }
    // repack v (DS pipe is in-order per wave: prior reads complete first)
    #pragma unroll
    for (int nt = 0; nt < 4; ++nt) {
        #pragma unroll
        for (int r = 0; r < 4; ++r)
            rpw[(quad * 4 + r) * 72 + nt * 16 + l16] = (_Float16)(av[nt][r]);
    }
    if (gr < NN) {
        *(half8*)&v[(size_t)gr * HD + cr]     = *(half8*)&rpw[mr * 72 + cr];
        *(half8*)&v[(size_t)gr * HD + cr + 8] = *(half8*)&rpw[mr * 72 + cr + 8];
    }
}

__global__ __launch_bounds__(256) void uv_slim(
        const float* __restrict__ x,
        const _Float16* __restrict__ Wuh, const _Float16* __restrict__ Wul,
        const _Float16* __restrict__ Wvh, const _Float16* __restrict__ Wvl,
        const float* __restrict__ bias,
        _Float16* __restrict__ u, _Float16* __restrict__ v) {
    __shared__ UvLds L;
    uv_body(L, blockIdx.x, x, Wuh, Wul, Wvh, Wvl, bias, u, v);
}

// ---------------- fill + first uv fused ------------------------------------
__global__ __launch_bounds__(256) void k_fill_uv(
        const int* __restrict__ ei, const float* __restrict__ ef,
        const int* __restrict__ ofs, const uchar2* __restrict__ rank,
        unsigned* __restrict__ em_val, int* __restrict__ ec_val,
        const float* __restrict__ x,
        const _Float16* __restrict__ Wuh, const _Float16* __restrict__ Wul,
        const _Float16* __restrict__ Wvh, const _Float16* __restrict__ Wvl,
        const float* __restrict__ bias,
        _Float16* __restrict__ u, _Float16* __restrict__ v) {
    __shared__ UvLds L;
    if (blockIdx.x < GB_CNT) {
        // fill (no atomics): em value = dst<<16 | fp16(ef) bits; ec value = src
        int e = blockIdx.x * 256 + threadIdx.x;   // grid exact: e < NE
        int src = ei[e];
        int dst = ei[NE + e];
        int o = e / PER;
        uchar2 r = rank[e];
        int p1 = ofs[o * NN + src] + r.x;
        unsigned short eb = __half_as_ushort(__float2half_rn(ef[e]));
        em_val[p1] = ((unsigned)dst << 16) | (unsigned)eb;
        int p2 = ofs[4 * NN + dst] + r.y - NE;
        ec_val[p2] = src;
    } else {
        uv_body(L, blockIdx.x - GB_CNT, x, Wuh, Wul, Wvh, Wvl, bias, u, v);
    }
}

// load 8 consecutive halves (16B aligned) -> 8 floats
__device__ __forceinline__ void load_h8(const __half* p, float* o) {
    float4 r = *(const float4*)p;
    __half2 h0 = *reinterpret_cast<__half2*>(&r.x);
    __half2 h1 = *reinterpret_cast<__half2*>(&r.y);
    __half2 h2 = *reinterpret_cast<__half2*>(&r.z);
    __half2 h3 = *reinterpret_cast<__half2*>(&r.w);
    float2 f0 = __half22float2(h0), f1 = __half22float2(h1);
    float2 f2 = __half22float2(h2), f3 = __half22float2(h3);
    o[0] = f0.x; o[1] = f0.y; o[2] = f1.x; o[3] = f1.y;
    o[4] = f2.x; o[5] = f2.y; o[6] = f3.x; o[7] = f3.y;
}

// convert an already-loaded 16B of halves -> 8 floats
__device__ __forceinline__ void cvt_h8(float4 r, float* o) {
    __half2 h0 = *reinterpret_cast<__half2*>(&r.x);
    __half2 h1 = *reinterpret_cast<__half2*>(&r.y);
    __half2 h2 = *reinterpret_cast<__half2*>(&r.z);
    __half2 h3 = *reinterpret_cast<__half2*>(&r.w);
    float2 f0 = __half22float2(h0), f1 = __half22float2(h1);
    float2 f2 = __half22float2(h2), f3 = __half22float2(h3);
    o[0] = f0.x; o[1] = f0.y; o[2] = f1.x; o[3] = f1.y;
    o[4] = f2.x; o[5] = f2.y; o[6] = f3.x; o[7] = f3.y;
}

// ---------------- emulsion edge pass + fold --------------------------------
// 8 nodes/wave, 8 lanes/node, 8 features/lane. Software-pipelined: next
// pair's index + 128B u-row prefetched (raw float4) while current pair is
// consumed -> gather latency hidden behind VALU; VGPR stays <=64.
// x[n] = (x[n] + sum_e relu(u[dst]+v[n]+ef*we)) / 2   (node-local update)
__device__ __forceinline__ void em_consume(
        unsigned e, float4 r, const float* vn, const float* wef, float* acc) {
    float uj[8];
    cvt_h8(r, uj);
    float ef = __half2float(__ushort_as_half((unsigned short)(e & 0xffff)));
    #pragma unroll
    for (int j = 0; j < 8; ++j)
        acc[j] += fmaxf(uj[j] + vn[j] + ef * wef[j], 0.f);
}

__global__ __launch_bounds__(256) void em_edge(
        const unsigned* __restrict__ em_val, const int* __restrict__ ofs,
        const __half* __restrict__ u, const __half* __restrict__ v,
        const float* __restrict__ we, float* __restrict__ x, int order) {
    int t = threadIdx.x;
    int node = blockIdx.x * 32 + (t >> 3);
    if (node >= NN) return;
    int f0 = (t & 7) * 8;
    int key = order * NN + node;
    int s0 = ofs[key], s1 = ofs[key + 1];
    float vn[8], wef[8], acc[8] = {};
    load_h8(&v[(size_t)node * HD + f0], vn);
    *(float4*)&wef[0] = *(const float4*)&we[f0];
    *(float4*)&wef[4] = *(const float4*)&we[f0 + 4];
    int p = s0, n = s1 - s0;
    unsigned ea = 0, eb = 0;
    float4 ra, rb;
    if (n >= 2) {
        ea = em_val[p]; eb = em_val[p + 1];
        ra = *(const float4*)&u[(size_t)(ea >> 16) * HD + f0];
        rb = *(const float4*)&u[(size_t)(eb >> 16) * HD + f0];
    }
    for (; p + 4 <= s1; p += 2) {
        unsigned na = em_val[p + 2], nb = em_val[p + 3];
        float4 qa = *(const float4*)&u[(size_t)(na >> 16) * HD + f0];
        float4 qb = *(const float4*)&u[(size_t)(nb >> 16) * HD + f0];
        em_consume(ea, ra, vn, wef, acc);
        em_consume(eb, rb, vn, wef, acc);
        ea = na; eb = nb; ra = qa; rb = qb;
    }
    if (n >= 2) {
        em_consume(ea, ra, vn, wef, acc);
        em_consume(eb, rb, vn, wef, acc);
        p += 2;
    }
    if (p < s1) {
        unsigned e0 = em_val[p];
        float4 r0 = *(const float4*)&u[(size_t)(e0 >> 16) * HD + f0];
        em_consume(e0, r0, vn, wef, acc);
    }
    float xr[8];
    *(float4*)&xr[0] = *(const float4*)&x[(size_t)node * HD + f0];
    *(float4*)&xr[4] = *(const float4*)&x[(size_t)node * HD + f0 + 4];
    #pragma unroll
    for (int j = 0; j < 8; ++j) xr[j] = (xr[j] + acc[j]) * 0.5f;
    *(float4*)&x[(size_t)node * HD + f0] = *(float4*)&xr[0];
    *(float4*)&x[(size_t)node * HD + f0 + 4] = *(float4*)&xr[4];
}

// ---------------- edge conv pass -------------------------------------------
// max_e relu(u[n]+v[src]) == relu(u[n] + max_e v[src])  (fp-exact). Pipelined
// like em_edge; empty segment -> 0.
__device__ __forceinline__ void ec_consume(float4 r, float* m) {
    float vj[8];
    cvt_h8(r, vj);
    #pragma unroll
    for (int j = 0; j < 8; ++j) m[j] = fmaxf(m[j], vj[j]);
}

__global__ __launch_bounds__(256) void ec_edge(
        const int* __restrict__ ec_val, const int* __restrict__ ofs,
        const __half* __restrict__ u, const __half* __restrict__ v,
        float* __restrict__ x) {
    int t = threadIdx.x;
    int node = blockIdx.x * 32 + (t >> 3);
    if (node >= NN) return;
    int f0 = (t & 7) * 8;
    int s0 = ofs[4 * NN + node] - NE, s1 = ofs[4 * NN + node + 1] - NE;
    float o[8];
    int n = s1 - s0;
    if (n > 0) {
        float m[8];
        #pragma unroll
        for (int j = 0; j < 8; ++j) m[j] = -3.0e38f;
        int p = s0;
        float4 ra, rb;
        if (n >= 2) {
            int ia = ec_val[p], ib = ec_val[p + 1];
            ra = *(const float4*)&v[(size_t)ia * HD + f0];
            rb = *(const float4*)&v[(size_t)ib * HD + f0];
        }
        for (; p + 4 <= s1; p += 2) {
            int na = ec_val[p + 2], nb = ec_val[p + 3];
            float4 qa = *(const float4*)&v[(size_t)na * HD + f0];
            float4 qb = *(const float4*)&v[(size_t)nb * HD + f0];
            ec_consume(ra, m);
            ec_consume(rb, m);
            ra = qa; rb = qb;
        }
        if (n >= 2) {
            ec_consume(ra, m);
            ec_consume(rb, m);
            p += 2;
        }
        if (p < s1) {
            int i0 = ec_val[p];
            float4 r0 = *(const float4*)&v[(size_t)i0 * HD + f0];
            ec_consume(r0, m);
        }
        float un[8];
        load_h8(&u[(size_t)node * HD + f0], un);
        #pragma unroll
        for (int j = 0; j < 8; ++j) o[j] = fmaxf(un[j] + m[j], 0.f);
    } else {
        #pragma unroll
        for (int j = 0; j < 8; ++j) o[j] = 0.f;
    }
    *(float4*)&x[(size_t)node * HD + f0] = *(float4*)&o[0];
    *(float4*)&x[(size_t)node * HD + f0 + 4] = *(float4*)&o[4];
}

// ---------------- linear: x = relu(x @ W + b), scalar fp32 ------------------
template<int K>
__global__ __launch_bounds__(256) void lin_kernel(
        const float* __restrict__ xin,
        const float* __restrict__ W, const float* __restrict__ bias,
        float* __restrict__ xout) {
    __shared__ float xs[64][K + 1];
    int t = threadIdx.x;
    int n0 = blockIdx.x * 64;
    for (int idx = t; idx < 64 * K; idx += 256) {
        int n = idx / K, k = idx - n * K;
        int g = n0 + n;
        xs[n][k] = (g < NN) ? xin[(size_t)g * K + k] : 0.f;
    }
    __syncthreads();
    int ng = t >> 4;
    int f0 = (t & 15) * 4;
    float acc[4][4] = {};
    for (int k = 0; k < K; ++k) {
        float4 w4 = *(const float4*)&W[k * HD + f0];
        #pragma unroll
        for (int j = 0; j < 4; ++j) {
            float xv = xs[ng * 4 + j][k];
            acc[j][0] += xv * w4.x; acc[j][1] += xv * w4.y;
            acc[j][2] += xv * w4.z; acc[j][3] += xv * w4.w;
        }
    }
    float4 b4 = *(const float4*)&bias[f0];
    #pragma unroll
    for (int j = 0; j < 4; ++j) {
        int g = n0 + ng * 4 + j;
        if (g < NN) {
            float4 o;
            o.x = fmaxf(acc[j][0] + b4.x, 0.f);
            o.y = fmaxf(acc[j][1] + b4.y, 0.f);
            o.z = fmaxf(acc[j][2] + b4.z, 0.f);
            o.w = fmaxf(acc[j][3] + b4.w, 0.f);
            *(float4*)&xout[(size_t)g * HD + f0] = o;
        }
    }
}

// ---------------- output projection ----------------------------------------
__global__ __launch_bounds__(256) void out_kernel(
        const float* __restrict__ x, const float* __restrict__ W,
        const float* __restrict__ bias, float* __restrict__ out) {
    int n = blockIdx.x * 256 + threadIdx.x;
    if (n >= NN) return;
    float xr[HD];
    #pragma unroll
    for (int k = 0; k < HD; k += 4) {
        float4 t4 = *(const float4*)&x[(size_t)n * HD + k];
        xr[k] = t4.x; xr[k + 1] = t4.y; xr[k + 2] = t4.z; xr[k + 3] = t4.w;
    }
    #pragma unroll
    for (int f = 0; f < 10; ++f) {
        float acc = bias[f];
        #pragma unroll
        for (int k = 0; k < HD; ++k) acc += xr[k] * W[k * 10 + f];
        out[(size_t)n * 10 + f] = acc;
    }
}

extern "C" void kernel_launch(void* const* d_in, const int* in_sizes, int n_in,
                              void* d_out, int out_size, void* d_ws, size_t ws_size,
                              hipStream_t stream) {
    const float* x_in  = (const float*)d_in[0];
    const int*   ei    = (const int*)d_in[1];
    const float* ef    = (const float*)d_in[2];
    const float* lw[3] = {(const float*)d_in[3], (const float*)d_in[5], (const float*)d_in[7]};
    const float* lb[3] = {(const float*)d_in[4], (const float*)d_in[6], (const float*)d_in[8]};
    const float* em_w  = (const float*)d_in[9];
    const float* em_b  = (const float*)d_in[10];
    const float* ec_w  = (const float*)d_in[11];
    const float* ec_b  = (const float*)d_in[12];
    const float* ow    = (const float*)d_in[13];
    const float* ob    = (const float*)d_in[14];
    float* out = (float*)d_out;

    char* wsb = (char*)d_ws;
    size_t off = 0;
    auto alloc = [&](size_t bytes) {
        void* p = wsb + off;
        off = (off + bytes + 255) & ~(size_t)255;
        return p;
    };
    float*     x      = (float*)alloc((size_t)NN * HD * 4);
    _Float16*  u      = (_Float16*)alloc((size_t)NN * HD * 2);
    _Float16*  v      = (_Float16*)alloc((size_t)NN * HD * 2);
    int*       cnt    = (int*)alloc((size_t)NKEY * 4);
    int*       ofs    = (int*)alloc((size_t)NKEY * 4);
    int*       bsum   = (int*)alloc((size_t)1024 * 4);
    uchar2*    rank   = (uchar2*)alloc((size_t)NE * 2);
    unsigned*  em_val = (unsigned*)alloc((size_t)NE * 4);
    int*       ec_val = (int*)alloc((size_t)NE * 4);
    _Float16*  wh     = (_Float16*)alloc((size_t)24 * 4096 * 2);
    (void)ws_size; (void)in_sizes; (void)n_in; (void)out_size;

    const int gb_n8 = (NN + 31) / 32;   // 1563

    // ---- CSR build + weight prep + lin0 (fused front) ----
    hipMemsetAsync(cnt, 0, (size_t)NKEY * 4, stream);
    k_front<<<GB_CNT + GB_PREP + GB_LIN, 256, 0, stream>>>(
        ei, cnt, rank, em_w, ec_w, wh, x_in, lw[0], lb[0], x);
    scan_blk<<<GB_KEYS, 256, 0, stream>>>(cnt, bsum);
    scan_fin2<<<GB_KEYS, 256, 0, stream>>>(cnt, bsum, ofs);

    // fill fused with layer-0/order-0 uv GEMM
    k_fill_uv<<<GB_CNT + GB_LIN, 256, 0, stream>>>(
        ei, ef, ofs, rank, em_val, ec_val, x,
        wh, wh + (size_t)12 * 4096, wh + (size_t)3 * 4096, wh + (size_t)15 * 4096,
        em_b, u, v);

    // ---- network ----
    for (int i = 0; i < 3; ++i) {
        const _Float16* Wuh = wh + (size_t)i * 4096;
        const _Float16* Wvh = wh + (size_t)(3 + i) * 4096;
        const _Float16* Wul = wh + (size_t)(12 + i) * 4096;
        const _Float16* Wvl = wh + (size_t)(15 + i) * 4096;
        const float* bi = em_b + (size_t)i * HD;
        const float* we = em_w + (size_t)i * 129 * HD + 128 * HD;
        for (int o = 0; o < 4; ++o) {
            if (!(i == 0 && o == 0))
                uv_slim<<<GB_LIN, 256, 0, stream>>>(x, Wuh, Wul, Wvh, Wvl, bi, u, v);
            em_edge<<<gb_n8, 256, 0, stream>>>(em_val, ofs, (const __half*)u,
                                               (const __half*)v, we, x, o);
        }
        if (i < 2)
            lin_kernel<64><<<GB_LIN, 256, 0, stream>>>(x, lw[i + 1], lb[i + 1], x);
    }

    for (int j = 0; j < 3; ++j) {
        const _Float16* Wuh = wh + (size_t)(6 + j) * 4096;
        const _Float16* Wvh = wh + (size_t)(9 + j) * 4096;
        const _Float16* Wul = wh + (size_t)(18 + j) * 4096;
        const _Float16* Wvl = wh + (size_t)(21 + j) * 4096;
        const float* bj = ec_b + (size_t)j * HD;
        uv_slim<<<GB_LIN, 256, 0, stream>>>(x, Wuh, Wul, Wvh, Wvl, bj, u, v);
        ec_edge<<<gb_n8, 256, 0, stream>>>(ec_val, ofs, (const __half*)u,
                                           (const __half*)v, x);
    }

    out_kernel<<<(NN + 255) / 256, 256, 0, stream>>>(x, ow, ob, out);
}